// Round 8
// baseline (2657.316 us; speedup 1.0000x reference)
//
#include <hip/hip_runtime.h>
#include <math.h>

// Problem constants (from reference)
#define NN 5000
#define NNP 5120    // padded rows for GEMM A-operand OOB staging
#define NE 50000
#define NEE 55000   // edges + self loops
#define NG 8
#define NH 4

typedef __attribute__((ext_vector_type(8))) _Float16 half8;
typedef __attribute__((ext_vector_type(4))) _Float16 half4;
typedef __attribute__((ext_vector_type(4))) float floatx4;

// ---------------- utility device functions ----------------

__device__ inline float waveSum(float v) {
    #pragma unroll
    for (int o = 32; o > 0; o >>= 1) v += __shfl_xor(v, o, 64);
    return v;
}
__device__ inline float waveMax(float v) {
    #pragma unroll
    for (int o = 32; o > 0; o >>= 1) v = fmaxf(v, __shfl_xor(v, o, 64));
    return v;
}

// async global->LDS DMA, 16B per lane; lds dest is wave-uniform base + lane*16
__device__ __forceinline__ void gload_lds16(const _Float16* g, _Float16* l) {
    __builtin_amdgcn_global_load_lds(
        (__attribute__((address_space(1))) void*)g,
        (__attribute__((address_space(3))) void*)l,
        16, 0, 0);
}

// ---------------- fp32 -> fp16 conversion ----------------

__global__ void k_cvtA(const float* __restrict__ X, _Float16* __restrict__ A0, int n) {
    int i = blockIdx.x * 256 + threadIdx.x;
    if (i >= n) return;
    A0[i] = (_Float16)X[i];
}

// Wl and Wr (K x M fp32) -> B0 fp16 TRANSPOSED: [WlT | WrT] each (M x K).
__global__ __launch_bounds__(256) void k_cvtWT2(const float* __restrict__ Wl,
        const float* __restrict__ Wr, _Float16* __restrict__ B0, int K, int M)
{
    __shared__ float tile[32][33];
    const float* W = blockIdx.z ? Wr : Wl;
    _Float16* dst = B0 + (size_t)blockIdx.z * M * K;
    int m0 = blockIdx.x * 32, k0 = blockIdx.y * 32;
    int tx = threadIdx.x & 31, ty = threadIdx.x >> 5;
    #pragma unroll
    for (int i = 0; i < 4; ++i)
        tile[ty + 8 * i][tx] = W[(size_t)(k0 + ty + 8 * i) * M + m0 + tx];
    __syncthreads();
    #pragma unroll
    for (int i = 0; i < 4; ++i) {
        int mm = ty + 8 * i, kk = tx;
        dst[(size_t)(m0 + mm) * K + kk + k0] = (_Float16)tile[kk][mm];
    }
}

// ====== 256x256 / BK=64 / 8-wave SINGLE-BUFFER GEMM (2 blocks/CU) ==========
// R4-R7 post-mortem: schedule variants (12/6 sync events, balanced reads,
// counted vmcnt) all landed 142-155us because the 128KB dbuf locks occupancy
// to 1 block/CU -> every barrier/gate/LDS-burst is whole-CU dead time (no
// co-resident block to hide it; m114 implicit-overlap mechanism absent).
// R8: SINGLE 64KB buffer -> 2 blocks/CU (16 waves). Per tile:
//   read ALL frags to regs (24 b128) | barrier (WAR: reads done before DMA
//   overwrites) | issue stage(t+1) over same buffer + 64 MFMA | vmcnt(0)
//   (free: loads had the full MFMA window ~2.4-5k cy >> 900cy HBM) | barrier.
// 3 sync events/tile, and the co-resident block overlaps all residual stalls.
// LDS chunk swizzle (both-sides, m173): global chunk (c^row&7), linear dest;
// reads XOR the same key -> conflict-free ds_read_b128 (measured 0).
// Epilogue: C staged/stored in two 128-row passes (64KB each).
__global__ __launch_bounds__(512, 4) void gemm256_mfma_f16(
    const _Float16* __restrict__ A0, const _Float16* __restrict__ B0,
    const float* __restrict__ biasL, const float* __restrict__ biasR,
    int Nhalf, _Float16* __restrict__ C,
    int Mrows, int K, int N)
{
    // [ A 256*64 | B 256*64 ] halfs = 64 KB
    __shared__ __align__(16) _Float16 smem[32768];

    const int tid  = threadIdx.x;
    const int wave = tid >> 6;
    const int lane = tid & 63;
    const int wr = wave >> 2;      // 0..1  (M half within a 128-row quadrant)
    const int wc = wave & 3;       // 0..3  (N quarter within a quadrant)
    const int rowBase = blockIdx.y * 256;
    const int colBase = blockIdx.x * 256;

    floatx4 acc[2][2][4][2];
    #pragma unroll
    for (int qa = 0; qa < 2; ++qa)
        #pragma unroll
        for (int qb = 0; qb < 2; ++qb)
            #pragma unroll
            for (int f = 0; f < 4; ++f)
                #pragma unroll
                for (int g = 0; g < 2; ++g)
                    acc[qa][qb][f][g] = (floatx4){0.f, 0.f, 0.f, 0.f};

    // staging: wave w stages rows h*128 + w*16 .. +16 (2 calls of 8 rows)
    // for each h half of A and of B -> 8 calls/wave/tile.
    // lane -> row lane>>3, global chunk (lane&7)^(lane>>3), linear LDS dest.
    const int srow   = lane >> 3;
    const int schunk = ((lane & 7) ^ srow) << 3;   // halfs
    const _Float16* gA = A0 + (size_t)(rowBase + wave * 16 + srow) * K + schunk;
    const _Float16* gB = B0 + (size_t)(colBase + wave * 16 + srow) * K + schunk;
    const size_t rstep = (size_t)8 * K;
    const size_t hstep = (size_t)128 * K;

    auto stageA = [&](int h, int kt) {
        _Float16* l = &smem[(h * 128 + wave * 16) * 64];
        const _Float16* g = gA + (size_t)h * hstep + (size_t)kt * 64;
        gload_lds16(g, l);
        gload_lds16(g + rstep, l + 512);
    };
    auto stageB = [&](int h, int kt) {
        _Float16* l = &smem[16384 + (h * 128 + wave * 16) * 64];
        const _Float16* g = gB + (size_t)h * hstep + (size_t)kt * 64;
        gload_lds16(g, l);
        gload_lds16(g + rstep, l + 512);
    };

    const int lm  = lane & 15;
    const int key = lane & 7;
    const int kg  = lane >> 4;

    half8 af0[4][2];   // A-frags QA=0
    half8 af1[4][2];   // A-frags QA=1
    half8 bf0[2][2];   // B-frags QB=0
    half8 bf1[2][2];   // B-frags QB=1

    auto readA = [&](int QA, half8 (&af)[4][2]) {
        #pragma unroll
        for (int f = 0; f < 4; ++f)
            #pragma unroll
            for (int s = 0; s < 2; ++s) {
                int row = QA * 128 + wr * 64 + f * 16 + lm;
                int ch = (s * 4 + kg) ^ key;
                af[f][s] = *(const half8*)&smem[row * 64 + ch * 8];
            }
    };
    auto readB = [&](int QB, half8 (&bf)[2][2]) {
        #pragma unroll
        for (int g = 0; g < 2; ++g)
            #pragma unroll
            for (int s = 0; s < 2; ++s) {
                int row = QB * 128 + wc * 32 + g * 16 + lm;
                int ch = (s * 4 + kg) ^ key;
                bf[g][s] = *(const half8*)&smem[16384 + row * 64 + ch * 8];
            }
    };
    auto mfma16 = [&](half8 (&af)[4][2], half8 (&bf)[2][2], floatx4 (&ac)[4][2]) {
        __builtin_amdgcn_s_setprio(1);
        #pragma unroll
        for (int f = 0; f < 4; ++f)
            #pragma unroll
            for (int g = 0; g < 2; ++g)
                #pragma unroll
                for (int s = 0; s < 2; ++s)
                    ac[f][g] = __builtin_amdgcn_mfma_f32_16x16x32_f16(
                        af[f][s], bf[g][s], ac[f][g], 0, 0, 0);
        __builtin_amdgcn_s_setprio(0);
    };

    // prologue: stage tile 0, drain, barrier
    stageA(0, 0); stageA(1, 0); stageB(0, 0); stageB(1, 0);
    asm volatile("s_waitcnt vmcnt(0)" ::: "memory");
    __builtin_amdgcn_s_barrier();

    const int nk = K >> 6;
    for (int t = 0; t < nk; ++t) {
        // read every fragment of tile t into registers
        readA(0, af0); readA(1, af1); readB(0, bf0); readB(1, bf1);
        __builtin_amdgcn_s_barrier();            // all reads done (WAR)
        if (t + 1 < nk) {                        // overwrite buffer with t+1
            stageA(0, t + 1); stageA(1, t + 1);
            stageB(0, t + 1); stageB(1, t + 1);
        }
        mfma16(af0, bf0, acc[0][0]);
        mfma16(af0, bf1, acc[0][1]);
        mfma16(af1, bf0, acc[1][0]);
        mfma16(af1, bf1, acc[1][1]);
        if (t + 1 < nk) {
            asm volatile("s_waitcnt vmcnt(0)" ::: "memory");  // t+1 landed
            __builtin_amdgcn_s_barrier();
        }
    }
    __builtin_amdgcn_s_barrier();                // final reads all done

    // ---- coalesced epilogue: two 128-row passes through the 64KB LDS ----
    // 32B-granule XOR by (row>>2)&7: 4 lane-groups -> 4 distinct bank
    // quadrants; bijective per row.
    _Float16* Ct = smem;   // [128][256] halfs per pass
    const int cq = (lane >> 4) * 4;
    const int r0 = tid >> 5;           // 0..15
    const int cc = (tid & 31) * 8;     // halfs within row
    const int gg = cc >> 4;
    for (int qa = 0; qa < 2; ++qa) {
        #pragma unroll
        for (int qb = 0; qb < 2; ++qb)
            #pragma unroll
            for (int g = 0; g < 2; ++g) {
                int col = qb * 128 + wc * 32 + g * 16 + lm;
                int gcol = colBase + col;
                float bv = (gcol < Nhalf) ? biasL[gcol] : biasR[gcol - Nhalf];
                #pragma unroll
                for (int f = 0; f < 4; ++f)
                    #pragma unroll
                    for (int r = 0; r < 4; ++r) {
                        int row = wr * 64 + f * 16 + cq + r;   // 0..127 local
                        int gi = (col >> 4) ^ ((row >> 2) & 7);
                        Ct[row * 256 + gi * 16 + (col & 15)] =
                            (_Float16)(acc[qa][qb][f][g][r] + bv);
                    }
            }
        __syncthreads();
        // 512 threads store 16 rows/pass (row = 512B contiguous), 8 passes
        #pragma unroll
        for (int ps = 0; ps < 8; ++ps) {
            int row = ps * 16 + r0;
            int grow = rowBase + qa * 128 + row;
            if (grow < Mrows) {
                int gp = gg ^ ((row >> 2) & 7);
                half8 v = *(const half8*)&Ct[row * 256 + gp * 16 + (cc & 15)];
                *(half8*)&C[(size_t)grow * N + colBase + cc] = v;
            }
        }
        __syncthreads();   // stores done before next pass overwrites LDS
    }
}

// ---------------- 128x128 MFMA GEMM (proven R2 kernel; layer-3) ------------
__global__ __launch_bounds__(256) void gemm_mfma_f16(
    const _Float16* __restrict__ A0, const _Float16* __restrict__ B0,
    const float* __restrict__ biasL, const float* __restrict__ biasR,
    int Nhalf, _Float16* __restrict__ C,
    int Mrows, int K, int N)
{
    __shared__ __align__(16) _Float16 smem[2 * 2 * 128 * 32];
    _Float16* As = smem;
    _Float16* Bs = smem + 2 * 128 * 32;

    const int tid = threadIdx.x;
    const int wave = tid >> 6;
    const int lane = tid & 63;
    const int wm = (wave >> 1) * 64;
    const int wn = (wave & 1) * 64;
    const int lm = lane & 15;
    const int swz = (((lane >> 4) ^ ((lane >> 1) & 3)) << 3);

    const int rowBase = blockIdx.y * 128;
    const int colBase = blockIdx.x * 128;

    floatx4 acc[4][4];
    #pragma unroll
    for (int i = 0; i < 4; ++i)
        #pragma unroll
        for (int j = 0; j < 4; ++j)
            acc[i][j] = (floatx4){0.f, 0.f, 0.f, 0.f};

    const int sr = lane >> 2;
    const int scol = (((lane & 3) ^ ((lane >> 3) & 3)) << 3);
    const _Float16* gA = A0 + (size_t)(rowBase + wave * 32 + sr) * K + scol;
    const _Float16* gB = B0 + (size_t)(colBase + wave * 32 + sr) * K + scol;
    const size_t skip16 = (size_t)16 * K;
    const int lo0 = (wave * 32) * 32;
    const int lo1 = (wave * 32 + 16) * 32;

    gload_lds16(gA, &As[lo0]);
    gload_lds16(gA + skip16, &As[lo1]);
    gload_lds16(gB, &Bs[lo0]);
    gload_lds16(gB + skip16, &Bs[lo1]);
    __syncthreads();

    const int nk = K >> 5;
    for (int t = 0; t < nk; ++t) {
        const int p = t & 1;
        const int po = p * 128 * 32;
        if (t + 1 < nk) {
            const int k1 = (t + 1) << 5;
            const int qo = (p ^ 1) * 128 * 32;
            gload_lds16(gA + k1, &As[qo + lo0]);
            gload_lds16(gA + skip16 + k1, &As[qo + lo1]);
            gload_lds16(gB + k1, &Bs[qo + lo0]);
            gload_lds16(gB + skip16 + k1, &Bs[qo + lo1]);
        }
        half8 a0[4], b0[4];
        #pragma unroll
        for (int i = 0; i < 4; ++i) {
            a0[i] = *(const half8*)&As[po + (wm + i * 16 + lm) * 32 + swz];
            b0[i] = *(const half8*)&Bs[po + (wn + i * 16 + lm) * 32 + swz];
        }
        #pragma unroll
        for (int i = 0; i < 4; ++i)
            #pragma unroll
            for (int j = 0; j < 4; ++j)
                acc[i][j] = __builtin_amdgcn_mfma_f32_16x16x32_f16(a0[i], b0[j], acc[i][j], 0, 0, 0);
        __syncthreads();
    }

    _Float16* Ct = smem;
    const int cq = (lane >> 4) * 4;
    #pragma unroll
    for (int j = 0; j < 4; ++j) {
        int col = wn + j * 16 + lm;
        int gcol = colBase + col;
        float bv = (gcol < Nhalf) ? biasL[gcol] : biasR[gcol - Nhalf];
        #pragma unroll
        for (int i = 0; i < 4; ++i) {
            int row = wm + i * 16 + cq;
            #pragma unroll
            for (int r = 0; r < 4; ++r) {
                int rr = row + r;
                Ct[rr * 128 + (col ^ (((rr >> 2) & 7) << 4))] = (_Float16)(acc[i][j][r] + bv);
            }
        }
    }
    __syncthreads();
    const int r0 = tid >> 4;
    const int cc = (tid & 15) * 8;
    #pragma unroll
    for (int ps = 0; ps < 8; ++ps) {
        int row = ps * 16 + r0;
        int grow = rowBase + row;
        if (grow < Mrows) {
            half8 v = *(const half8*)&Ct[row * 128 + (cc ^ (((row >> 2) & 7) << 4))];
            *(half8*)&C[(size_t)grow * N + colBase + cc] = v;
        }
    }
}

// ---------------- CSR build ----------------

__global__ void k_build_zero(const int* __restrict__ ei, int* __restrict__ src,
                             int* __restrict__ dst, int* __restrict__ cnt) {
    int i = blockIdx.x * 256 + threadIdx.x;
    if (i < NE) { src[i] = ei[i]; dst[i] = ei[NE + i]; }
    else if (i < NEE) { src[i] = i - NE; dst[i] = i - NE; }
    if (i < NN) cnt[i] = 0;
}

__global__ void k_count(const int* __restrict__ dst, int* __restrict__ cnt) {
    int i = blockIdx.x * 256 + threadIdx.x;
    if (i < NEE) atomicAdd(&cnt[dst[i]], 1);
}

__global__ __launch_bounds__(256) void k_scan(const int* __restrict__ cnt,
                                              int* __restrict__ off, int* __restrict__ cur) {
    __shared__ int partial[256];
    __shared__ int ppre[257];
    int t = threadIdx.x;
    const int chunk = (NN + 255) / 256;
    int lo = t * chunk, hi = min(NN, (t + 1) * chunk);
    int s = 0;
    for (int i = lo; i < hi; ++i) s += cnt[i];
    partial[t] = s;
    __syncthreads();
    if (t == 0) {
        int acc = 0;
        for (int i = 0; i < 256; ++i) { ppre[i] = acc; acc += partial[i]; }
        ppre[256] = acc;
    }
    __syncthreads();
    int acc = ppre[t];
    for (int i = lo; i < hi; ++i) { off[i] = acc; cur[i] = acc; acc += cnt[i]; }
    if (t == 0) off[NN] = ppre[256];
}

__global__ void k_fill(const int* __restrict__ src, const int* __restrict__ dst,
                       int* __restrict__ cur, int* __restrict__ slist) {
    int e = blockIdx.x * 256 + threadIdx.x;
    if (e < NEE) { int p = atomicAdd(&cur[dst[e]], 1); slist[p] = src[e]; }
}

__global__ void k_zero_misc(int* __restrict__ gstart, float* __restrict__ hpool) {
    int i = blockIdx.x * 256 + threadIdx.x;
    if (i < 2 * NG) gstart[i] = 0;
    if (i < NG * 256) hpool[i] = 0.f;
}

// ---------------- fused GATv2 edge pipeline (fp16 activations) -------------
// xlr is the fused GEMM output: row n = [xl(n) | xr(n)], stride LD = 2*NH*C.
// depth-2 prefetch (3 buffers): hides slist scalar-load + row gather latency.
template<int C>
__global__ __launch_bounds__(256) void k_gat_fused(
    const _Float16* __restrict__ xlr, const float* __restrict__ att,
    const int* __restrict__ eoff, const int* __restrict__ slist,
    const float* __restrict__ bias, _Float16* __restrict__ out)
{
    constexpr int LD = 2 * NH * C;          // fused GEMM row stride (halfs)
    constexpr int CH = (C >= 512) ? 8 : 4;  // halfs per load per lane
    constexpr int NC = C / (64 * CH);       // chunks per head-row
    constexpr int PL = NC * CH;             // elems per lane
    __shared__ float red[NH * C];
    const int n = blockIdx.x;
    const int h = threadIdx.x >> 6;
    const int lane = threadIdx.x & 63;

    float xrv[PL], attv[PL], acc[PL];
    {
        const _Float16* xrrow = xlr + (size_t)n * LD + NH * C + h * C + lane * CH;
        const float* ah = att + h * C + lane * CH;
        #pragma unroll
        for (int c = 0; c < NC; ++c) {
            if constexpr (CH == 8) {
                half8 hv = *(const half8*)(xrrow + c * 64 * CH);
                #pragma unroll
                for (int e = 0; e < 8; ++e) xrv[c * 8 + e] = (float)hv[e];
            } else {
                half4 hv = *(const half4*)(xrrow + c * 64 * CH);
                #pragma unroll
                for (int e = 0; e < 4; ++e) xrv[c * 4 + e] = (float)hv[e];
            }
            #pragma unroll
            for (int e = 0; e < CH; e += 4) {
                float4 a4 = *(const float4*)(ah + c * 64 * CH + e);
                attv[c * CH + e + 0] = a4.x; attv[c * CH + e + 1] = a4.y;
                attv[c * CH + e + 2] = a4.z; attv[c * CH + e + 3] = a4.w;
            }
        }
        #pragma unroll
        for (int e = 0; e < PL; ++e) acc[e] = 0.f;
    }

    float m = -INFINITY, den = 0.f;
    const int start = eoff[n], end = eoff[n + 1];

    _Float16 bufA[PL], bufB[PL], bufC[PL];
    auto ldrow = [&](int s, _Float16* buf) {
        const _Float16* p = xlr + (size_t)s * LD + h * C + lane * CH;
        #pragma unroll
        for (int c = 0; c < NC; ++c) {
            if constexpr (CH == 8)
                *(half8*)&buf[c * 8] = *(const half8*)(p + c * 64 * CH);
            else
                *(half4*)&buf[c * 4] = *(const half4*)(p + c * 64 * CH);
        }
    };

    if (start < end) ldrow(slist[start], bufA);
    if (start + 1 < end) ldrow(slist[start + 1], bufB);
    for (int j = start; j < end; ++j) {
        if (j + 2 < end) ldrow(slist[j + 2], bufC);   // depth-2 prefetch
        float xv[PL];
        float ps = 0.f;
        #pragma unroll
        for (int e = 0; e < PL; ++e) {
            xv[e] = (float)bufA[e];
            float v = xv[e] + xrv[e];
            v = v > 0.f ? v : 0.2f * v;
            ps = fmaf(v, attv[e], ps);
        }
        ps = waveSum(ps);
        float m_new = fmaxf(m, ps);
        float scale = expf(m - m_new);
        float ex = expf(ps - m_new);
        den = den * scale + ex;
        m = m_new;
        #pragma unroll
        for (int e = 0; e < PL; ++e)
            acc[e] = fmaf(ex, xv[e], acc[e] * scale);
        #pragma unroll
        for (int e = 0; e < PL; ++e) { bufA[e] = bufB[e]; bufB[e] = bufC[e]; }
    }

    float inv = 1.f / (den + 1e-16f);
    #pragma unroll
    for (int c = 0; c < NC; ++c) {
        int off = h * C + c * 64 * CH + lane * CH;
        #pragma unroll
        for (int e = 0; e < CH; e += 4) {
            float4 r;
            r.x = acc[c * CH + e + 0] * inv;
            r.y = acc[c * CH + e + 1] * inv;
            r.z = acc[c * CH + e + 2] * inv;
            r.w = acc[c * CH + e + 3] * inv;
            *(float4*)&red[off + e] = r;
        }
    }
    __syncthreads();

    int t = threadIdx.x;
    for (int c4 = t; c4 < C / 4; c4 += 256) {
        int c = c4 * 4;
        float4 r0 = *(const float4*)&red[0 * C + c];
        float4 r1 = *(const float4*)&red[1 * C + c];
        float4 r2 = *(const float4*)&red[2 * C + c];
        float4 r3 = *(const float4*)&red[3 * C + c];
        float4 bv = *(const float4*)(bias + c);
        half4 o;
        o[0] = (_Float16)fmaxf((r0.x + r1.x + r2.x + r3.x) * 0.25f + bv.x, 0.f);
        o[1] = (_Float16)fmaxf((r0.y + r1.y + r2.y + r3.y) * 0.25f + bv.y, 0.f);
        o[2] = (_Float16)fmaxf((r0.z + r1.z + r2.z + r3.z) * 0.25f + bv.z, 0.f);
        o[3] = (_Float16)fmaxf((r0.w + r1.w + r2.w + r3.w) * 0.25f + bv.w, 0.f);
        *(half4*)(out + (size_t)n * C + c) = o;
    }
}

// ---------------- gate + pool + MLP ----------------

__global__ __launch_bounds__(128) void k_gate(
    const _Float16* __restrict__ x, const float* __restrict__ Wg0,
    const float* __restrict__ bg0, const float* __restrict__ Wg1,
    const float* __restrict__ bg1, float* __restrict__ g)
{
    int n = blockIdx.x;
    int t = threadIdx.x;
    __shared__ float xs[256];
    __shared__ float wsum[2];
    const _Float16* xp = x + (size_t)n * 256;
    xs[t] = (float)xp[t]; xs[t + 128] = (float)xp[t + 128];
    __syncthreads();
    float acc = bg0[t];
    for (int k = 0; k < 256; ++k) acc = fmaf(xs[k], Wg0[k * 128 + t], acc);
    acc = acc > 0.f ? acc : 0.f;
    float prod = acc * Wg1[t];
    prod = waveSum(prod);
    if ((t & 63) == 0) wsum[t >> 6] = prod;
    __syncthreads();
    if (t == 0) g[n] = wsum[0] + wsum[1] + bg1[0];
}

__global__ void k_group_bounds(const int* __restrict__ batch, int* __restrict__ gstart,
                               int* __restrict__ gend) {
    int n = blockIdx.x * 256 + threadIdx.x;
    if (n >= NN) return;
    int b = batch[n];
    if (n == 0 || batch[n - 1] != b) gstart[b] = n;
    if (n == NN - 1 || batch[n + 1] != b) gend[b] = n + 1;
}

// per-group softmax stats: m[g], invden[g]
__global__ __launch_bounds__(256) void k_pool_stats(
    const float* __restrict__ g, const int* __restrict__ gstart,
    const int* __restrict__ gend, float* __restrict__ mOut,
    float* __restrict__ invdenOut)
{
    int gi = blockIdx.x;
    int t = threadIdx.x;
    int s0 = gstart[gi], e0 = gend[gi];
    __shared__ float red[4];
    float mx = -1e30f;
    for (int n = s0 + t; n < e0; n += 256) mx = fmaxf(mx, g[n]);
    float wm = waveMax(mx);
    if ((t & 63) == 0) red[t >> 6] = wm;
    __syncthreads();
    float m = fmaxf(fmaxf(red[0], red[1]), fmaxf(red[2], red[3]));
    __syncthreads();
    float sm = 0.f;
    for (int n = s0 + t; n < e0; n += 256) sm += expf(g[n] - m);
    sm = waveSum(sm);
    if ((t & 63) == 0) red[t >> 6] = sm;
    __syncthreads();
    if (t == 0) {
        float den = red[0] + red[1] + red[2] + red[3] + 1e-16f;
        mOut[gi] = m;
        invdenOut[gi] = 1.f / den;
    }
}

#define PCH 16
__global__ __launch_bounds__(256) void k_pool_acc(
    const _Float16* __restrict__ x, const float* __restrict__ g,
    const int* __restrict__ batch, const float* __restrict__ m,
    const float* __restrict__ invden, float* __restrict__ hpool)
{
    int base = blockIdx.x * PCH;
    int t = threadIdx.x;
    float acc = 0.f;
    int cur = -1;
    for (int i = 0; i < PCH; ++i) {
        int n = base + i;
        if (n >= NN) break;
        int b = batch[n];
        if (b != cur) {
            if (cur >= 0) atomicAdd(&hpool[cur * 256 + t], acc);
            cur = b; acc = 0.f;
        }
        float w = expf(g[n] - m[b]) * invden[b];
        acc = fmaf(w, (float)x[(size_t)n * 256 + t], acc);
    }
    if (cur >= 0) atomicAdd(&hpool[cur * 256 + t], acc);
}

__global__ __launch_bounds__(256) void k_mlp(
    const float* __restrict__ hpool,
    const float* __restrict__ Wm0, const float* __restrict__ bm0,
    const float* __restrict__ Wm1, const float* __restrict__ bm1,
    const float* __restrict__ Wm2, const float* __restrict__ bm2,
    const float* __restrict__ Wm3, const float* __restrict__ bm3,
    const float* __restrict__ Wm4, const float* __restrict__ bm4,
    float* __restrict__ out)
{
    __shared__ float bufA[8 * 256];
    __shared__ float bufB[8 * 128];
    int t = threadIdx.x;
    for (int i = t; i < 8 * 256; i += 256) bufA[i] = hpool[i];
    __syncthreads();
    for (int i = t; i < 8 * 128; i += 256) {
        int r = i >> 7, c = i & 127;
        float acc = bm0[c];
        for (int k = 0; k < 256; ++k) acc = fmaf(bufA[r * 256 + k], Wm0[k * 128 + c], acc);
        bufB[i] = fmaxf(acc, 0.f);
    }
    __syncthreads();
    for (int i = t; i < 8 * 64; i += 256) {
        int r = i >> 6, c = i & 63;
        float acc = bm1[c];
        for (int k = 0; k < 128; ++k) acc = fmaf(bufB[r * 128 + k], Wm1[k * 64 + c], acc);
        bufA[i] = fmaxf(acc, 0.f);
    }
    __syncthreads();
    for (int i = t; i < 8 * 32; i += 256) {
        int r = i >> 5, c = i & 31;
        float acc = bm2[c];
        for (int k = 0; k < 64; ++k) acc = fmaf(bufA[r * 64 + k], Wm2[k * 32 + c], acc);
        bufB[i] = fmaxf(acc, 0.f);
    }
    __syncthreads();
    for (int i = t; i < 8 * 16; i += 256) {
        int r = i >> 4, c = i & 15;
        float acc = bm3[c];
        for (int k = 0; k < 32; ++k) acc = fmaf(bufB[r * 32 + k], Wm3[k * 16 + c], acc);
        bufA[i] = fmaxf(acc, 0.f);
    }
    __syncthreads();
    if (t < 8) {
        float acc = bm4[0];
        for (int k = 0; k < 16; ++k) acc = fmaf(bufA[t * 16 + k], Wm4[k], acc);
        out[t] = acc;
    }
}

// ---------------- host orchestration ----------------

static void run_gat_layer(const _Float16* ain, int K, int C,
                          const float* Wl, const float* bl,
                          const float* Wr, const float* br,
                          const float* att, const float* bias,
                          _Float16* wb0, _Float16* xlr,
                          const int* eoff, const int* slist,
                          _Float16* xout, hipStream_t stream)
{
    int HC = NH * C;
    dim3 tgrid(HC / 32, K / 32, 2);
    k_cvtWT2<<<tgrid, 256, 0, stream>>>(Wl, Wr, wb0, K, HC);
    // fused Wl/Wr GEMM: N = 2*HC, output row n = [xl(n) | xr(n)]
    if (C >= 512) {
        dim3 ggrid(2 * HC / 256, NNP / 256);
        gemm256_mfma_f16<<<ggrid, 512, 0, stream>>>(ain, wb0, bl, br, HC, xlr, NN, K, 2 * HC);
    } else {
        dim3 ggrid(2 * HC / 128, NNP / 128);
        gemm_mfma_f16<<<ggrid, 256, 0, stream>>>(ain, wb0, bl, br, HC, xlr, NN, K, 2 * HC);
    }

    if (C == 1024)
        k_gat_fused<1024><<<NN, 256, 0, stream>>>(xlr, att, eoff, slist, bias, xout);
    else if (C == 512)
        k_gat_fused<512><<<NN, 256, 0, stream>>>(xlr, att, eoff, slist, bias, xout);
    else
        k_gat_fused<256><<<NN, 256, 0, stream>>>(xlr, att, eoff, slist, bias, xout);
}

extern "C" void kernel_launch(void* const* d_in, const int* in_sizes, int n_in,
                              void* d_out, int out_size, void* d_ws, size_t ws_size,
                              hipStream_t stream) {
    const float* x      = (const float*)d_in[0];
    const int* ei       = (const int*)d_in[1];
    const int* batch    = (const int*)d_in[2];
    const float* Wl1 = (const float*)d_in[3];  const float* bl1 = (const float*)d_in[4];
    const float* Wr1 = (const float*)d_in[5];  const float* br1 = (const float*)d_in[6];
    const float* att1= (const float*)d_in[7];  const float* b1  = (const float*)d_in[8];
    const float* Wl2 = (const float*)d_in[9];  const float* bl2 = (const float*)d_in[10];
    const float* Wr2 = (const float*)d_in[11]; const float* br2 = (const float*)d_in[12];
    const float* att2= (const float*)d_in[13]; const float* b2  = (const float*)d_in[14];
    const float* Wl3 = (const float*)d_in[15]; const float* bl3 = (const float*)d_in[16];
    const float* Wr3 = (const float*)d_in[17]; const float* br3 = (const float*)d_in[18];
    const float* att3= (const float*)d_in[19]; const float* b3  = (const float*)d_in[20];
    const float* Wm0 = (const float*)d_in[21]; const float* bm0 = (const float*)d_in[22];
    const float* Wm1 = (const float*)d_in[23]; const float* bm1 = (const float*)d_in[24];
    const float* Wm2 = (const float*)d_in[25]; const float* bm2 = (const float*)d_in[26];
    const float* Wm3 = (const float*)d_in[27]; const float* bm3 = (const float*)d_in[28];
    const float* Wm4 = (const float*)d_in[29]; const float* bm4 = (const float*)d_in[30];
    const float* Wg0 = (const float*)d_in[31]; const float* bg0 = (const float*)d_in[32];
    const float* Wg1 = (const float*)d_in[33]; const float* bg1 = (const float*)d_in[34];
    float* out = (float*)d_out;

    // workspace carve (float units = 4B); fp16 buffers 16B-aligned, padded rows
    float* ws = (float*)d_ws;
    size_t o = 0;
    _Float16* xlr = (_Float16*)(ws + o); o += (size_t)NNP * 8192 / 2;  // fused [xl|xr], layer1 sized
    _Float16* x1  = (_Float16*)(ws + o); o += (size_t)NNP * 1024 / 2;
    _Float16* x2  = (_Float16*)(ws + o); o += (size_t)NNP * 512 / 2;
    _Float16* x3  = (_Float16*)(ws + o); o += (size_t)NNP * 256 / 2;
    _Float16* a0p = (_Float16*)(ws + o); o += (size_t)NNP * 1536 / 2;
    _Float16* wb0 = (_Float16*)(ws + o); o += (size_t)8192 * 1536 / 2; // [WlT | WrT], layer1 sized
    int* srcA    = (int*)(ws + o); o += NEE;
    int* dstA    = (int*)(ws + o); o += NEE;
    int* cnt     = (int*)(ws + o); o += NN;
    int* eoff    = (int*)(ws + o); o += NN + 1;
    int* cur     = (int*)(ws + o); o += NN;
    int* slist   = (int*)(ws + o); o += NEE;
    float* g     = ws + o; o += NN;
    int* gstart  = (int*)(ws + o); o += NG;
    int* gend    = (int*)(ws + o); o += NG;
    float* gm    = ws + o; o += NG;
    float* ginv  = ws + o; o += NG;
    float* hpool = ws + o; o += NG * 256;

    // build CSR by dst (slist holds src node ids) + zero cnt in one pass
    int ebB = (NEE + 255) / 256;
    k_build_zero<<<ebB, 256, 0, stream>>>(ei, srcA, dstA, cnt);
    k_count<<<ebB, 256, 0, stream>>>(dstA, cnt);
    k_scan<<<1, 256, 0, stream>>>(cnt, eoff, cur);
    k_fill<<<ebB, 256, 0, stream>>>(srcA, dstA, cur, slist);
    // zero gstart/gend + hpool early (independent of everything above)
    k_zero_misc<<<NG, 256, 0, stream>>>(gstart, hpool);

    // layer-1 input -> fp16 (only conversion needed; later layers emit fp16)
    int nA = NN * 1536;
    k_cvtA<<<(nA + 255) / 256, 256, 0, stream>>>(x, a0p, nA);

    // three GATv2 layers
    run_gat_layer(a0p, 1536, 1024, Wl1, bl1, Wr1, br1, att1, b1,
                  wb0, xlr, eoff, slist, x1, stream);
    run_gat_layer(x1,  1024, 512,  Wl2, bl2, Wr2, br2, att2, b2,
                  wb0, xlr, eoff, slist, x2, stream);
    run_gat_layer(x2,  512,  256,  Wl3, bl3, Wr3, br3, att3, b3,
                  wb0, xlr, eoff, slist, x3, stream);

    // gate + pool + MLP
    k_gate<<<NN, 128, 0, stream>>>(x3, Wg0, bg0, Wg1, bg1, g);
    k_group_bounds<<<(NN + 255) / 256, 256, 0, stream>>>(batch, gstart, gend);
    k_pool_stats<<<NG, 256, 0, stream>>>(g, gstart, gend, gm, ginv);
    k_pool_acc<<<(NN + PCH - 1) / PCH, 256, 0, stream>>>(x3, g, batch, gm, ginv, hpool);
    k_mlp<<<1, 256, 0, stream>>>(hpool, Wm0, bm0, Wm1, bm1, Wm2, bm2,
                                 Wm3, bm3, Wm4, bm4, out);
}

// Round 9
// 661.785 us; speedup vs baseline: 4.0154x; 4.0154x over previous
//
#include <hip/hip_runtime.h>
#include <math.h>

// Problem constants (from reference)
#define NN 5000
#define NNP 5120    // padded rows for GEMM A-operand OOB staging
#define NE 50000
#define NEE 55000   // edges + self loops
#define NG 8
#define NH 4

typedef __attribute__((ext_vector_type(8))) _Float16 half8;
typedef __attribute__((ext_vector_type(4))) _Float16 half4;
typedef __attribute__((ext_vector_type(4))) float floatx4;

// ---------------- utility device functions ----------------

__device__ inline float waveSum(float v) {
    #pragma unroll
    for (int o = 32; o > 0; o >>= 1) v += __shfl_xor(v, o, 64);
    return v;
}
__device__ inline float waveMax(float v) {
    #pragma unroll
    for (int o = 32; o > 0; o >>= 1) v = fmaxf(v, __shfl_xor(v, o, 64));
    return v;
}

// async global->LDS DMA, 16B per lane; lds dest is wave-uniform base + lane*16
__device__ __forceinline__ void gload_lds16(const _Float16* g, _Float16* l) {
    __builtin_amdgcn_global_load_lds(
        (__attribute__((address_space(1))) void*)g,
        (__attribute__((address_space(3))) void*)l,
        16, 0, 0);
}

template<int N>
__device__ __forceinline__ void vmgate() {
    if constexpr (N == 0) asm volatile("s_waitcnt vmcnt(0)" ::: "memory");
    else if constexpr (N == 2) asm volatile("s_waitcnt vmcnt(2)" ::: "memory");
    else if constexpr (N == 4) asm volatile("s_waitcnt vmcnt(4)" ::: "memory");
    // N < 0: no gate
}

// ---------------- fp32 -> fp16 conversion ----------------

__global__ void k_cvtA(const float* __restrict__ X, _Float16* __restrict__ A0, int n) {
    int i = blockIdx.x * 256 + threadIdx.x;
    if (i >= n) return;
    A0[i] = (_Float16)X[i];
}

// Wl and Wr (K x M fp32) -> B0 fp16 TRANSPOSED: [WlT | WrT] each (M x K).
__global__ __launch_bounds__(256) void k_cvtWT2(const float* __restrict__ Wl,
        const float* __restrict__ Wr, _Float16* __restrict__ B0, int K, int M)
{
    __shared__ float tile[32][33];
    const float* W = blockIdx.z ? Wr : Wl;
    _Float16* dst = B0 + (size_t)blockIdx.z * M * K;
    int m0 = blockIdx.x * 32, k0 = blockIdx.y * 32;
    int tx = threadIdx.x & 31, ty = threadIdx.x >> 5;
    #pragma unroll
    for (int i = 0; i < 4; ++i)
        tile[ty + 8 * i][tx] = W[(size_t)(k0 + ty + 8 * i) * M + m0 + tx];
    __syncthreads();
    #pragma unroll
    for (int i = 0; i < 4; ++i) {
        int mm = ty + 8 * i, kk = tx;
        dst[(size_t)(m0 + mm) * K + kk + k0] = (_Float16)tile[kk][mm];
    }
}

// ============ 256x256 / BK=64 / 8-wave phase-split GEMM (R5-verified) ======
// MEASURED BEST: 142 us @ L1 (886 TF), VGPR 128, 0 bank conflicts (R5 bench).
// R8 lesson: __launch_bounds__(512,4) caps regs at 128/wave -> total spill
// (VGPR 64, 3.9GB scratch writes, 12x slower). The 256x256 tile's 128-f32
// accumulator makes 4 waves/EU impossible; this structure is pinned at
// 2 waves/EU, 1 block/CU. KEEP (512,2).
// Balanced 4/4/8/8 read phases; ph4 reads NEXT tile's af(QA0) (its Ah0 unit
// landed via end-ph3 gate). Uniform vmcnt(4) at every phase end; each gate
// waits on a unit issued 3 phases (~3000cy) earlier >> 900cy HBM latency.
// Ledger (units of 2 loads): entry {Bh1(t),Ah1(t)}; ph1 +Ah0(t+1) gate4 =>
// Bh1(t); ph2 +Bh0(t+1) gate4 => Ah1(t); ph3 +Bh1(t+1) gate4 => Ah0(t+1);
// ph4 +Ah1(t+1) gate4 => Bh0(t+1).
// LDS chunk swizzle (both-sides, m173): global chunk (c^row&7), linear dest;
// reads XOR the same key -> conflict-free ds_read_b128 (measured 0).
__global__ __launch_bounds__(512, 2) void gemm256_mfma_f16(
    const _Float16* __restrict__ A0, const _Float16* __restrict__ B0,
    const float* __restrict__ biasL, const float* __restrict__ biasR,
    int Nhalf, _Float16* __restrict__ C,
    int Mrows, int K, int N)
{
    // [dbuf][ A 256*64 | B 256*64 ] halfs = 128 KB total
    __shared__ __align__(16) _Float16 smem[2 * 32768];

    const int tid  = threadIdx.x;
    const int wave = tid >> 6;
    const int lane = tid & 63;
    const int wr = wave >> 2;      // 0..1  (M half within a quadrant)
    const int wc = wave & 3;       // 0..3  (N quarter within a quadrant)
    const int rowBase = blockIdx.y * 256;
    const int colBase = blockIdx.x * 256;

    floatx4 acc[2][2][4][2];
    #pragma unroll
    for (int qa = 0; qa < 2; ++qa)
        #pragma unroll
        for (int qb = 0; qb < 2; ++qb)
            #pragma unroll
            for (int f = 0; f < 4; ++f)
                #pragma unroll
                for (int g = 0; g < 2; ++g)
                    acc[qa][qb][f][g] = (floatx4){0.f, 0.f, 0.f, 0.f};

    // staging: wave w stages rows h*128 + w*16 .. +16 (2 calls of 8 rows).
    // lane -> row lane>>3, global chunk (lane&7)^(lane>>3), linear LDS dest.
    const int srow   = lane >> 3;
    const int schunk = ((lane & 7) ^ srow) << 3;   // halfs
    const _Float16* gA = A0 + (size_t)(rowBase + wave * 16 + srow) * K + schunk;
    const _Float16* gB = B0 + (size_t)(colBase + wave * 16 + srow) * K + schunk;
    const size_t rstep = (size_t)8 * K;
    const size_t hstep = (size_t)128 * K;

    auto stageA = [&](int b, int h, int kt) {
        _Float16* l = &smem[b * 32768 + (h * 128 + wave * 16) * 64];
        const _Float16* g = gA + (size_t)h * hstep + (size_t)kt * 64;
        gload_lds16(g, l);
        gload_lds16(g + rstep, l + 512);
    };
    auto stageB = [&](int b, int h, int kt) {
        _Float16* l = &smem[b * 32768 + 16384 + (h * 128 + wave * 16) * 64];
        const _Float16* g = gB + (size_t)h * hstep + (size_t)kt * 64;
        gload_lds16(g, l);
        gload_lds16(g + rstep, l + 512);
    };

    const int lm  = lane & 15;
    const int key = lane & 7;
    const int kg  = lane >> 4;

    half8 af0[4][2];   // A-frags QA=0 (read in PREV tile's ph4; used ph1,ph2)
    half8 af1[4][2];   // A-frags QA=1 (read ph3; used ph3,ph4)
    half8 bf0[2][2];   // B-frags QB=0 (read ph1; used ph1,ph3)
    half8 bf1[2][2];   // B-frags QB=1 (read ph2; used ph2,ph4)

    auto readA = [&](const _Float16* Ab, int QA, half8 (&af)[4][2]) {
        #pragma unroll
        for (int f = 0; f < 4; ++f)
            #pragma unroll
            for (int s = 0; s < 2; ++s) {
                int row = QA * 128 + wr * 64 + f * 16 + lm;
                int ch = (s * 4 + kg) ^ key;
                af[f][s] = *(const half8*)&Ab[row * 64 + ch * 8];
            }
    };
    auto readB = [&](const _Float16* Bb, int QB, half8 (&bf)[2][2]) {
        #pragma unroll
        for (int g = 0; g < 2; ++g)
            #pragma unroll
            for (int s = 0; s < 2; ++s) {
                int row = QB * 128 + wc * 32 + g * 16 + lm;
                int ch = (s * 4 + kg) ^ key;
                bf[g][s] = *(const half8*)&Bb[row * 64 + ch * 8];
            }
    };
    auto mfma16 = [&](half8 (&af)[4][2], half8 (&bf)[2][2], floatx4 (&ac)[4][2]) {
        __builtin_amdgcn_s_setprio(1);
        #pragma unroll
        for (int f = 0; f < 4; ++f)
            #pragma unroll
            for (int g = 0; g < 2; ++g)
                #pragma unroll
                for (int s = 0; s < 2; ++s)
                    ac[f][g] = __builtin_amdgcn_mfma_f32_16x16x32_f16(
                        af[f][s], bf[g][s], ac[f][g], 0, 0, 0);
        __builtin_amdgcn_s_setprio(0);
    };

    // prologue: stage tile 0 in steady-state age order; Ah0,Bh0 landed;
    // pre-read af0 (tile 0 QA0).
    stageA(0, 0, 0); stageB(0, 0, 0); stageB(0, 1, 0); stageA(0, 1, 0);
    vmgate<4>();
    __builtin_amdgcn_s_barrier();
    readA(&smem[0], 0, af0);

    const int nk = K >> 6;
    for (int t = 0; t < nk - 1; ++t) {
        const int b = t & 1;
        const _Float16* Ab  = &smem[b * 32768];
        const _Float16* Bb  = Ab + 16384;
        const _Float16* AbN = &smem[(b ^ 1) * 32768];
        // ph1: 4 reads (bf0) | stage Ah0' | MFMA(0,0) | gate->Bh1(t)
        readB(Bb, 0, bf0);
        stageA(b ^ 1, 0, t + 1);
        __builtin_amdgcn_s_barrier();
        mfma16(af0, bf0, acc[0][0]);
        vmgate<4>();
        __builtin_amdgcn_s_barrier();
        // ph2: 4 reads (bf1) | stage Bh0' | MFMA(0,1) | gate->Ah1(t)
        readB(Bb, 1, bf1);
        stageB(b ^ 1, 0, t + 1);
        __builtin_amdgcn_s_barrier();
        mfma16(af0, bf1, acc[0][1]);
        vmgate<4>();
        __builtin_amdgcn_s_barrier();
        // ph3: 8 reads (af1) | stage Bh1' | MFMA(1,0) | gate->Ah0'(t+1)
        readA(Ab, 1, af1);
        stageB(b ^ 1, 1, t + 1);
        __builtin_amdgcn_s_barrier();
        mfma16(af1, bf0, acc[1][0]);
        vmgate<4>();
        __builtin_amdgcn_s_barrier();
        // ph4: 8 reads (af0 of NEXT tile, Ah0' landed) | stage Ah1' |
        //      MFMA(1,1) | gate->Bh0'(t+1)
        readA(AbN, 0, af0);
        stageA(b ^ 1, 1, t + 1);
        __builtin_amdgcn_s_barrier();
        mfma16(af1, bf1, acc[1][1]);
        vmgate<4>();
        __builtin_amdgcn_s_barrier();
    }
    {   // last tile: no staging; entry outstanding = {Bh1, Ah1} (4 loads)
        const int b = (nk - 1) & 1;
        const _Float16* Ab = &smem[b * 32768];
        const _Float16* Bb = Ab + 16384;
        readB(Bb, 0, bf0);
        __builtin_amdgcn_s_barrier();
        mfma16(af0, bf0, acc[0][0]);
        vmgate<2>();                  // Bh1 landed
        __builtin_amdgcn_s_barrier();
        readB(Bb, 1, bf1);
        __builtin_amdgcn_s_barrier();
        mfma16(af0, bf1, acc[0][1]);
        vmgate<0>();                  // Ah1 landed
        __builtin_amdgcn_s_barrier();
        readA(Ab, 1, af1);
        __builtin_amdgcn_s_barrier();
        mfma16(af1, bf0, acc[1][0]);
        __builtin_amdgcn_s_barrier();
        mfma16(af1, bf1, acc[1][1]);
        __builtin_amdgcn_s_barrier();
    }

    // ---- coalesced epilogue: stage 256x256 C-tile in the dead LDS ----
    // 32B-granule XOR by (row>>2)&7: 4 lane-groups -> 4 distinct bank
    // quadrants; bijective per row.
    _Float16* Ct = smem;
    const int cq = (lane >> 4) * 4;
    #pragma unroll
    for (int qb = 0; qb < 2; ++qb)
        #pragma unroll
        for (int g = 0; g < 2; ++g) {
            int col = qb * 128 + wc * 32 + g * 16 + lm;
            int gcol = colBase + col;
            float bv = (gcol < Nhalf) ? biasL[gcol] : biasR[gcol - Nhalf];
            #pragma unroll
            for (int qa = 0; qa < 2; ++qa)
                #pragma unroll
                for (int f = 0; f < 4; ++f)
                    #pragma unroll
                    for (int r = 0; r < 4; ++r) {
                        int row = qa * 128 + wr * 64 + f * 16 + cq + r;
                        int gi = (col >> 4) ^ ((row >> 2) & 7);
                        Ct[row * 256 + gi * 16 + (col & 15)] =
                            (_Float16)(acc[qa][qb][f][g][r] + bv);
                    }
        }
    __syncthreads();
    // 512 threads store 16 rows/pass (row = 512B contiguous), 16 passes
    const int r0 = tid >> 5;           // 0..15
    const int cc = (tid & 31) * 8;     // halfs within row
    const int gg = cc >> 4;
    #pragma unroll
    for (int ps = 0; ps < 16; ++ps) {
        int row = ps * 16 + r0;
        int grow = rowBase + row;
        if (grow < Mrows) {
            int gp = gg ^ ((row >> 2) & 7);
            half8 v = *(const half8*)&Ct[row * 256 + gp * 16 + (cc & 15)];
            *(half8*)&C[(size_t)grow * N + colBase + cc] = v;
        }
    }
}

// ---------------- 128x128 MFMA GEMM (proven R2 kernel; layer-3) ------------
__global__ __launch_bounds__(256) void gemm_mfma_f16(
    const _Float16* __restrict__ A0, const _Float16* __restrict__ B0,
    const float* __restrict__ biasL, const float* __restrict__ biasR,
    int Nhalf, _Float16* __restrict__ C,
    int Mrows, int K, int N)
{
    __shared__ __align__(16) _Float16 smem[2 * 2 * 128 * 32];
    _Float16* As = smem;
    _Float16* Bs = smem + 2 * 128 * 32;

    const int tid = threadIdx.x;
    const int wave = tid >> 6;
    const int lane = tid & 63;
    const int wm = (wave >> 1) * 64;
    const int wn = (wave & 1) * 64;
    const int lm = lane & 15;
    const int swz = (((lane >> 4) ^ ((lane >> 1) & 3)) << 3);

    const int rowBase = blockIdx.y * 128;
    const int colBase = blockIdx.x * 128;

    floatx4 acc[4][4];
    #pragma unroll
    for (int i = 0; i < 4; ++i)
        #pragma unroll
        for (int j = 0; j < 4; ++j)
            acc[i][j] = (floatx4){0.f, 0.f, 0.f, 0.f};

    const int sr = lane >> 2;
    const int scol = (((lane & 3) ^ ((lane >> 3) & 3)) << 3);
    const _Float16* gA = A0 + (size_t)(rowBase + wave * 32 + sr) * K + scol;
    const _Float16* gB = B0 + (size_t)(colBase + wave * 32 + sr) * K + scol;
    const size_t skip16 = (size_t)16 * K;
    const int lo0 = (wave * 32) * 32;
    const int lo1 = (wave * 32 + 16) * 32;

    gload_lds16(gA, &As[lo0]);
    gload_lds16(gA + skip16, &As[lo1]);
    gload_lds16(gB, &Bs[lo0]);
    gload_lds16(gB + skip16, &Bs[lo1]);
    __syncthreads();

    const int nk = K >> 5;
    for (int t = 0; t < nk; ++t) {
        const int p = t & 1;
        const int po = p * 128 * 32;
        if (t + 1 < nk) {
            const int k1 = (t + 1) << 5;
            const int qo = (p ^ 1) * 128 * 32;
            gload_lds16(gA + k1, &As[qo + lo0]);
            gload_lds16(gA + skip16 + k1, &As[qo + lo1]);
            gload_lds16(gB + k1, &Bs[qo + lo0]);
            gload_lds16(gB + skip16 + k1, &Bs[qo + lo1]);
        }
        half8 a0[4], b0[4];
        #pragma unroll
        for (int i = 0; i < 4; ++i) {
            a0[i] = *(const half8*)&As[po + (wm + i * 16 + lm) * 32 + swz];
            b0[i] = *(const half8*)&Bs[po + (wn + i * 16 + lm) * 32 + swz];
        }
        #pragma unroll
        for (int i = 0; i < 4; ++i)
            #pragma unroll
            for (int j = 0; j < 4; ++j)
                acc[i][j] = __builtin_amdgcn_mfma_f32_16x16x32_f16(a0[i], b0[j], acc[i][j], 0, 0, 0);
        __syncthreads();
    }

    _Float16* Ct = smem;
    const int cq = (lane >> 4) * 4;
    #pragma unroll
    for (int j = 0; j < 4; ++j) {
        int col = wn + j * 16 + lm;
        int gcol = colBase + col;
        float bv = (gcol < Nhalf) ? biasL[gcol] : biasR[gcol - Nhalf];
        #pragma unroll
        for (int i = 0; i < 4; ++i) {
            int row = wm + i * 16 + cq;
            #pragma unroll
            for (int r = 0; r < 4; ++r) {
                int rr = row + r;
                Ct[rr * 128 + (col ^ (((rr >> 2) & 7) << 4))] = (_Float16)(acc[i][j][r] + bv);
            }
        }
    }
    __syncthreads();
    const int r0 = tid >> 4;
    const int cc = (tid & 15) * 8;
    #pragma unroll
    for (int ps = 0; ps < 8; ++ps) {
        int row = ps * 16 + r0;
        int grow = rowBase + row;
        if (grow < Mrows) {
            half8 v = *(const half8*)&Ct[row * 128 + (cc ^ (((row >> 2) & 7) << 4))];
            *(half8*)&C[(size_t)grow * N + colBase + cc] = v;
        }
    }
}

// ---------------- CSR build ----------------

__global__ void k_build_zero(const int* __restrict__ ei, int* __restrict__ src,
                             int* __restrict__ dst, int* __restrict__ cnt) {
    int i = blockIdx.x * 256 + threadIdx.x;
    if (i < NE) { src[i] = ei[i]; dst[i] = ei[NE + i]; }
    else if (i < NEE) { src[i] = i - NE; dst[i] = i - NE; }
    if (i < NN) cnt[i] = 0;
}

__global__ void k_count(const int* __restrict__ dst, int* __restrict__ cnt) {
    int i = blockIdx.x * 256 + threadIdx.x;
    if (i < NEE) atomicAdd(&cnt[dst[i]], 1);
}

__global__ __launch_bounds__(256) void k_scan(const int* __restrict__ cnt,
                                              int* __restrict__ off, int* __restrict__ cur) {
    __shared__ int partial[256];
    __shared__ int ppre[257];
    int t = threadIdx.x;
    const int chunk = (NN + 255) / 256;
    int lo = t * chunk, hi = min(NN, (t + 1) * chunk);
    int s = 0;
    for (int i = lo; i < hi; ++i) s += cnt[i];
    partial[t] = s;
    __syncthreads();
    if (t == 0) {
        int acc = 0;
        for (int i = 0; i < 256; ++i) { ppre[i] = acc; acc += partial[i]; }
        ppre[256] = acc;
    }
    __syncthreads();
    int acc = ppre[t];
    for (int i = lo; i < hi; ++i) { off[i] = acc; cur[i] = acc; acc += cnt[i]; }
    if (t == 0) off[NN] = ppre[256];
}

__global__ void k_fill(const int* __restrict__ src, const int* __restrict__ dst,
                       int* __restrict__ cur, int* __restrict__ slist) {
    int e = blockIdx.x * 256 + threadIdx.x;
    if (e < NEE) { int p = atomicAdd(&cur[dst[e]], 1); slist[p] = src[e]; }
}

__global__ void k_zero_misc(int* __restrict__ gstart, float* __restrict__ hpool) {
    int i = blockIdx.x * 256 + threadIdx.x;
    if (i < 2 * NG) gstart[i] = 0;
    if (i < NG * 256) hpool[i] = 0.f;
}

// ---------------- fused GATv2 edge pipeline (fp16 activations) -------------
// xlr is the fused GEMM output: row n = [xl(n) | xr(n)], stride LD = 2*NH*C.
// depth-2 prefetch (3 buffers): hides slist scalar-load + row gather latency.
template<int C>
__global__ __launch_bounds__(256) void k_gat_fused(
    const _Float16* __restrict__ xlr, const float* __restrict__ att,
    const int* __restrict__ eoff, const int* __restrict__ slist,
    const float* __restrict__ bias, _Float16* __restrict__ out)
{
    constexpr int LD = 2 * NH * C;          // fused GEMM row stride (halfs)
    constexpr int CH = (C >= 512) ? 8 : 4;  // halfs per load per lane
    constexpr int NC = C / (64 * CH);       // chunks per head-row
    constexpr int PL = NC * CH;             // elems per lane
    __shared__ float red[NH * C];
    const int n = blockIdx.x;
    const int h = threadIdx.x >> 6;
    const int lane = threadIdx.x & 63;

    float xrv[PL], attv[PL], acc[PL];
    {
        const _Float16* xrrow = xlr + (size_t)n * LD + NH * C + h * C + lane * CH;
        const float* ah = att + h * C + lane * CH;
        #pragma unroll
        for (int c = 0; c < NC; ++c) {
            if constexpr (CH == 8) {
                half8 hv = *(const half8*)(xrrow + c * 64 * CH);
                #pragma unroll
                for (int e = 0; e < 8; ++e) xrv[c * 8 + e] = (float)hv[e];
            } else {
                half4 hv = *(const half4*)(xrrow + c * 64 * CH);
                #pragma unroll
                for (int e = 0; e < 4; ++e) xrv[c * 4 + e] = (float)hv[e];
            }
            #pragma unroll
            for (int e = 0; e < CH; e += 4) {
                float4 a4 = *(const float4*)(ah + c * 64 * CH + e);
                attv[c * CH + e + 0] = a4.x; attv[c * CH + e + 1] = a4.y;
                attv[c * CH + e + 2] = a4.z; attv[c * CH + e + 3] = a4.w;
            }
        }
        #pragma unroll
        for (int e = 0; e < PL; ++e) acc[e] = 0.f;
    }

    float m = -INFINITY, den = 0.f;
    const int start = eoff[n], end = eoff[n + 1];

    _Float16 bufA[PL], bufB[PL], bufC[PL];
    auto ldrow = [&](int s, _Float16* buf) {
        const _Float16* p = xlr + (size_t)s * LD + h * C + lane * CH;
        #pragma unroll
        for (int c = 0; c < NC; ++c) {
            if constexpr (CH == 8)
                *(half8*)&buf[c * 8] = *(const half8*)(p + c * 64 * CH);
            else
                *(half4*)&buf[c * 4] = *(const half4*)(p + c * 64 * CH);
        }
    };

    if (start < end) ldrow(slist[start], bufA);
    if (start + 1 < end) ldrow(slist[start + 1], bufB);
    for (int j = start; j < end; ++j) {
        if (j + 2 < end) ldrow(slist[j + 2], bufC);   // depth-2 prefetch
        float xv[PL];
        float ps = 0.f;
        #pragma unroll
        for (int e = 0; e < PL; ++e) {
            xv[e] = (float)bufA[e];
            float v = xv[e] + xrv[e];
            v = v > 0.f ? v : 0.2f * v;
            ps = fmaf(v, attv[e], ps);
        }
        ps = waveSum(ps);
        float m_new = fmaxf(m, ps);
        float scale = expf(m - m_new);
        float ex = expf(ps - m_new);
        den = den * scale + ex;
        m = m_new;
        #pragma unroll
        for (int e = 0; e < PL; ++e)
            acc[e] = fmaf(ex, xv[e], acc[e] * scale);
        #pragma unroll
        for (int e = 0; e < PL; ++e) { bufA[e] = bufB[e]; bufB[e] = bufC[e]; }
    }

    float inv = 1.f / (den + 1e-16f);
    #pragma unroll
    for (int c = 0; c < NC; ++c) {
        int off = h * C + c * 64 * CH + lane * CH;
        #pragma unroll
        for (int e = 0; e < CH; e += 4) {
            float4 r;
            r.x = acc[c * CH + e + 0] * inv;
            r.y = acc[c * CH + e + 1] * inv;
            r.z = acc[c * CH + e + 2] * inv;
            r.w = acc[c * CH + e + 3] * inv;
            *(float4*)&red[off + e] = r;
        }
    }
    __syncthreads();

    int t = threadIdx.x;
    for (int c4 = t; c4 < C / 4; c4 += 256) {
        int c = c4 * 4;
        float4 r0 = *(const float4*)&red[0 * C + c];
        float4 r1 = *(const float4*)&red[1 * C + c];
        float4 r2 = *(const float4*)&red[2 * C + c];
        float4 r3 = *(const float4*)&red[3 * C + c];
        float4 bv = *(const float4*)(bias + c);
        half4 o;
        o[0] = (_Float16)fmaxf((r0.x + r1.x + r2.x + r3.x) * 0.25f + bv.x, 0.f);
        o[1] = (_Float16)fmaxf((r0.y + r1.y + r2.y + r3.y) * 0.25f + bv.y, 0.f);
        o[2] = (_Float16)fmaxf((r0.z + r1.z + r2.z + r3.z) * 0.25f + bv.z, 0.f);
        o[3] = (_Float16)fmaxf((r0.w + r1.w + r2.w + r3.w) * 0.25f + bv.w, 0.f);
        *(half4*)(out + (size_t)n * C + c) = o;
    }
}

// ---------------- gate + pool + MLP ----------------

__global__ __launch_bounds__(128) void k_gate(
    const _Float16* __restrict__ x, const float* __restrict__ Wg0,
    const float* __restrict__ bg0, const float* __restrict__ Wg1,
    const float* __restrict__ bg1, float* __restrict__ g)
{
    int n = blockIdx.x;
    int t = threadIdx.x;
    __shared__ float xs[256];
    __shared__ float wsum[2];
    const _Float16* xp = x + (size_t)n * 256;
    xs[t] = (float)xp[t]; xs[t + 128] = (float)xp[t + 128];
    __syncthreads();
    float acc = bg0[t];
    for (int k = 0; k < 256; ++k) acc = fmaf(xs[k], Wg0[k * 128 + t], acc);
    acc = acc > 0.f ? acc : 0.f;
    float prod = acc * Wg1[t];
    prod = waveSum(prod);
    if ((t & 63) == 0) wsum[t >> 6] = prod;
    __syncthreads();
    if (t == 0) g[n] = wsum[0] + wsum[1] + bg1[0];
}

__global__ void k_group_bounds(const int* __restrict__ batch, int* __restrict__ gstart,
                               int* __restrict__ gend) {
    int n = blockIdx.x * 256 + threadIdx.x;
    if (n >= NN) return;
    int b = batch[n];
    if (n == 0 || batch[n - 1] != b) gstart[b] = n;
    if (n == NN - 1 || batch[n + 1] != b) gend[b] = n + 1;
}

// per-group softmax stats: m[g], invden[g]
__global__ __launch_bounds__(256) void k_pool_stats(
    const float* __restrict__ g, const int* __restrict__ gstart,
    const int* __restrict__ gend, float* __restrict__ mOut,
    float* __restrict__ invdenOut)
{
    int gi = blockIdx.x;
    int t = threadIdx.x;
    int s0 = gstart[gi], e0 = gend[gi];
    __shared__ float red[4];
    float mx = -1e30f;
    for (int n = s0 + t; n < e0; n += 256) mx = fmaxf(mx, g[n]);
    float wm = waveMax(mx);
    if ((t & 63) == 0) red[t >> 6] = wm;
    __syncthreads();
    float m = fmaxf(fmaxf(red[0], red[1]), fmaxf(red[2], red[3]));
    __syncthreads();
    float sm = 0.f;
    for (int n = s0 + t; n < e0; n += 256) sm += expf(g[n] - m);
    sm = waveSum(sm);
    if ((t & 63) == 0) red[t >> 6] = sm;
    __syncthreads();
    if (t == 0) {
        float den = red[0] + red[1] + red[2] + red[3] + 1e-16f;
        mOut[gi] = m;
        invdenOut[gi] = 1.f / den;
    }
}

#define PCH 16
__global__ __launch_bounds__(256) void k_pool_acc(
    const _Float16* __restrict__ x, const float* __restrict__ g,
    const int* __restrict__ batch, const float* __restrict__ m,
    const float* __restrict__ invden, float* __restrict__ hpool)
{
    int base = blockIdx.x * PCH;
    int t = threadIdx.x;
    float acc = 0.f;
    int cur = -1;
    for (int i = 0; i < PCH; ++i) {
        int n = base + i;
        if (n >= NN) break;
        int b = batch[n];
        if (b != cur) {
            if (cur >= 0) atomicAdd(&hpool[cur * 256 + t], acc);
            cur = b; acc = 0.f;
        }
        float w = expf(g[n] - m[b]) * invden[b];
        acc = fmaf(w, (float)x[(size_t)n * 256 + t], acc);
    }
    if (cur >= 0) atomicAdd(&hpool[cur * 256 + t], acc);
}

__global__ __launch_bounds__(256) void k_mlp(
    const float* __restrict__ hpool,
    const float* __restrict__ Wm0, const float* __restrict__ bm0,
    const float* __restrict__ Wm1, const float* __restrict__ bm1,
    const float* __restrict__ Wm2, const float* __restrict__ bm2,
    const float* __restrict__ Wm3, const float* __restrict__ bm3,
    const float* __restrict__ Wm4, const float* __restrict__ bm4,
    float* __restrict__ out)
{
    __shared__ float bufA[8 * 256];
    __shared__ float bufB[8 * 128];
    int t = threadIdx.x;
    for (int i = t; i < 8 * 256; i += 256) bufA[i] = hpool[i];
    __syncthreads();
    for (int i = t; i < 8 * 128; i += 256) {
        int r = i >> 7, c = i & 127;
        float acc = bm0[c];
        for (int k = 0; k < 256; ++k) acc = fmaf(bufA[r * 256 + k], Wm0[k * 128 + c], acc);
        bufB[i] = fmaxf(acc, 0.f);
    }
    __syncthreads();
    for (int i = t; i < 8 * 64; i += 256) {
        int r = i >> 6, c = i & 63;
        float acc = bm1[c];
        for (int k = 0; k < 128; ++k) acc = fmaf(bufB[r * 128 + k], Wm1[k * 64 + c], acc);
        bufA[i] = fmaxf(acc, 0.f);
    }
    __syncthreads();
    for (int i = t; i < 8 * 32; i += 256) {
        int r = i >> 5, c = i & 31;
        float acc = bm2[c];
        for (int k = 0; k < 64; ++k) acc = fmaf(bufA[r * 64 + k], Wm2[k * 32 + c], acc);
        bufB[i] = fmaxf(acc, 0.f);
    }
    __syncthreads();
    for (int i = t; i < 8 * 16; i += 256) {
        int r = i >> 4, c = i & 15;
        float acc = bm3[c];
        for (int k = 0; k < 32; ++k) acc = fmaf(bufB[r * 32 + k], Wm3[k * 16 + c], acc);
        bufA[i] = fmaxf(acc, 0.f);
    }
    __syncthreads();
    if (t < 8) {
        float acc = bm4[0];
        for (int k = 0; k < 16; ++k) acc = fmaf(bufA[t * 16 + k], Wm4[k], acc);
        out[t] = acc;
    }
}

// ---------------- host orchestration ----------------

static void run_gat_layer(const _Float16* ain, int K, int C,
                          const float* Wl, const float* bl,
                          const float* Wr, const float* br,
                          const float* att, const float* bias,
                          _Float16* wb0, _Float16* xlr,
                          const int* eoff, const int* slist,
                          _Float16* xout, hipStream_t stream)
{
    int HC = NH * C;
    dim3 tgrid(HC / 32, K / 32, 2);
    k_cvtWT2<<<tgrid, 256, 0, stream>>>(Wl, Wr, wb0, K, HC);
    // fused Wl/Wr GEMM: N = 2*HC, output row n = [xl(n) | xr(n)]
    if (C >= 512) {
        dim3 ggrid(2 * HC / 256, NNP / 256);
        gemm256_mfma_f16<<<ggrid, 512, 0, stream>>>(ain, wb0, bl, br, HC, xlr, NN, K, 2 * HC);
    } else {
        dim3 ggrid(2 * HC / 128, NNP / 128);
        gemm_mfma_f16<<<ggrid, 256, 0, stream>>>(ain, wb0, bl, br, HC, xlr, NN, K, 2 * HC);
    }

    if (C == 1024)
        k_gat_fused<1024><<<NN, 256, 0, stream>>>(xlr, att, eoff, slist, bias, xout);
    else if (C == 512)
        k_gat_fused<512><<<NN, 256, 0, stream>>>(xlr, att, eoff, slist, bias, xout);
    else
        k_gat_fused<256><<<NN, 256, 0, stream>>>(xlr, att, eoff, slist, bias, xout);
}

extern "C" void kernel_launch(void* const* d_in, const int* in_sizes, int n_in,
                              void* d_out, int out_size, void* d_ws, size_t ws_size,
                              hipStream_t stream) {
    const float* x      = (const float*)d_in[0];
    const int* ei       = (const int*)d_in[1];
    const int* batch    = (const int*)d_in[2];
    const float* Wl1 = (const float*)d_in[3];  const float* bl1 = (const float*)d_in[4];
    const float* Wr1 = (const float*)d_in[5];  const float* br1 = (const float*)d_in[6];
    const float* att1= (const float*)d_in[7];  const float* b1  = (const float*)d_in[8];
    const float* Wl2 = (const float*)d_in[9];  const float* bl2 = (const float*)d_in[10];
    const float* Wr2 = (const float*)d_in[11]; const float* br2 = (const float*)d_in[12];
    const float* att2= (const float*)d_in[13]; const float* b2  = (const float*)d_in[14];
    const float* Wl3 = (const float*)d_in[15]; const float* bl3 = (const float*)d_in[16];
    const float* Wr3 = (const float*)d_in[17]; const float* br3 = (const float*)d_in[18];
    const float* att3= (const float*)d_in[19]; const float* b3  = (const float*)d_in[20];
    const float* Wm0 = (const float*)d_in[21]; const float* bm0 = (const float*)d_in[22];
    const float* Wm1 = (const float*)d_in[23]; const float* bm1 = (const float*)d_in[24];
    const float* Wm2 = (const float*)d_in[25]; const float* bm2 = (const float*)d_in[26];
    const float* Wm3 = (const float*)d_in[27]; const float* bm3 = (const float*)d_in[28];
    const float* Wm4 = (const float*)d_in[29]; const float* bm4 = (const float*)d_in[30];
    const float* Wg0 = (const float*)d_in[31]; const float* bg0 = (const float*)d_in[32];
    const float* Wg1 = (const float*)d_in[33]; const float* bg1 = (const float*)d_in[34];
    float* out = (float*)d_out;

    // workspace carve (float units = 4B); fp16 buffers 16B-aligned, padded rows
    float* ws = (float*)d_ws;
    size_t o = 0;
    _Float16* xlr = (_Float16*)(ws + o); o += (size_t)NNP * 8192 / 2;  // fused [xl|xr], layer1 sized
    _Float16* x1  = (_Float16*)(ws + o); o += (size_t)NNP * 1024 / 2;
    _Float16* x2  = (_Float16*)(ws + o); o += (size_t)NNP * 512 / 2;
    _Float16* x3  = (_Float16*)(ws + o); o += (size_t)NNP * 256 / 2;
    _Float16* a0p = (_Float16*)(ws + o); o += (size_t)NNP * 1536 / 2;
    _Float16* wb0 = (_Float16*)(ws + o); o += (size_t)8192 * 1536 / 2; // [WlT | WrT], layer1 sized
    int* srcA    = (int*)(ws + o); o += NEE;
    int* dstA    = (int*)(ws + o); o += NEE;
    int* cnt     = (int*)(ws + o); o += NN;
    int* eoff    = (int*)(ws + o); o += NN + 1;
    int* cur     = (int*)(ws + o); o += NN;
    int* slist   = (int*)(ws + o); o += NEE;
    float* g     = ws + o; o += NN;
    int* gstart  = (int*)(ws + o); o += NG;
    int* gend    = (int*)(ws + o); o += NG;
    float* gm    = ws + o; o += NG;
    float* ginv  = ws + o; o += NG;
    float* hpool = ws + o; o += NG * 256;

    // build CSR by dst (slist holds src node ids) + zero cnt in one pass
    int ebB = (NEE + 255) / 256;
    k_build_zero<<<ebB, 256, 0, stream>>>(ei, srcA, dstA, cnt);
    k_count<<<ebB, 256, 0, stream>>>(dstA, cnt);
    k_scan<<<1, 256, 0, stream>>>(cnt, eoff, cur);
    k_fill<<<ebB, 256, 0, stream>>>(srcA, dstA, cur, slist);
    // zero gstart/gend + hpool early (independent of everything above)
    k_zero_misc<<<NG, 256, 0, stream>>>(gstart, hpool);

    // layer-1 input -> fp16 (only conversion needed; later layers emit fp16)
    int nA = NN * 1536;
    k_cvtA<<<(nA + 255) / 256, 256, 0, stream>>>(x, a0p, nA);

    // three GATv2 layers
    run_gat_layer(a0p, 1536, 1024, Wl1, bl1, Wr1, br1, att1, b1,
                  wb0, xlr, eoff, slist, x1, stream);
    run_gat_layer(x1,  1024, 512,  Wl2, bl2, Wr2, br2, att2, b2,
                  wb0, xlr, eoff, slist, x2, stream);
    run_gat_layer(x2,  512,  256,  Wl3, bl3, Wr3, br3, att3, b3,
                  wb0, xlr, eoff, slist, x3, stream);

    // gate + pool + MLP
    k_gate<<<NN, 128, 0, stream>>>(x3, Wg0, bg0, Wg1, bg1, g);
    k_group_bounds<<<(NN + 255) / 256, 256, 0, stream>>>(batch, gstart, gend);
    k_pool_stats<<<NG, 256, 0, stream>>>(g, gstart, gend, gm, ginv);
    k_pool_acc<<<(NN + PCH - 1) / PCH, 256, 0, stream>>>(x3, g, batch, gm, ginv, hpool);
    k_mlp<<<1, 256, 0, stream>>>(hpool, Wm0, bm0, Wm1, bm1, Wm2, bm2,
                                 Wm3, bm3, Wm4, bm4, out);
}

// Round 10
// 635.988 us; speedup vs baseline: 4.1782x; 1.0406x over previous
//
#include <hip/hip_runtime.h>
#include <math.h>

// Problem constants (from reference)
#define NN 5000
#define NNP 5120    // padded rows for GEMM A-operand OOB staging
#define NE 50000
#define NEE 55000   // edges + self loops
#define NG 8
#define NH 4

typedef __attribute__((ext_vector_type(8))) _Float16 half8;
typedef __attribute__((ext_vector_type(4))) _Float16 half4;
typedef __attribute__((ext_vector_type(4))) float floatx4;

// ---------------- utility device functions ----------------

__device__ inline float waveSum(float v) {
    #pragma unroll
    for (int o = 32; o > 0; o >>= 1) v += __shfl_xor(v, o, 64);
    return v;
}
__device__ inline float waveMax(float v) {
    #pragma unroll
    for (int o = 32; o > 0; o >>= 1) v = fmaxf(v, __shfl_xor(v, o, 64));
    return v;
}

// async global->LDS DMA, 16B per lane; lds dest is wave-uniform base + lane*16
__device__ __forceinline__ void gload_lds16(const _Float16* g, _Float16* l) {
    __builtin_amdgcn_global_load_lds(
        (__attribute__((address_space(1))) void*)g,
        (__attribute__((address_space(3))) void*)l,
        16, 0, 0);
}

template<int N>
__device__ __forceinline__ void vmgate() {
    if constexpr (N == 0) asm volatile("s_waitcnt vmcnt(0)" ::: "memory");
    else if constexpr (N == 2) asm volatile("s_waitcnt vmcnt(2)" ::: "memory");
    else if constexpr (N == 4) asm volatile("s_waitcnt vmcnt(4)" ::: "memory");
    // N < 0: no gate
}

// ---------------- fp32 -> fp16 conversion ----------------

__global__ void k_cvtA(const float* __restrict__ X, _Float16* __restrict__ A0, int n) {
    int i = blockIdx.x * 256 + threadIdx.x;
    if (i >= n) return;
    A0[i] = (_Float16)X[i];
}

// att1/att2/att3 (fp32) -> packed fp16 [4096 | 2048 | 1024] halfs.
// GAT kernels are memory-bound; att was re-read per node as fp32 (80+40+20MB)
// -> fp16 halves that traffic.
__global__ void k_cvt_att3(const float* __restrict__ a1, const float* __restrict__ a2,
                           const float* __restrict__ a3, _Float16* __restrict__ d) {
    int i = blockIdx.x * 256 + threadIdx.x;
    if (i < 4096) d[i] = (_Float16)a1[i];
    else if (i < 6144) d[i] = (_Float16)a2[i - 4096];
    else if (i < 7168) d[i] = (_Float16)a3[i - 6144];
}

// Wl and Wr (K x M fp32) -> B0 fp16 TRANSPOSED: [WlT | WrT] each (M x K).
__global__ __launch_bounds__(256) void k_cvtWT2(const float* __restrict__ Wl,
        const float* __restrict__ Wr, _Float16* __restrict__ B0, int K, int M)
{
    __shared__ float tile[32][33];
    const float* W = blockIdx.z ? Wr : Wl;
    _Float16* dst = B0 + (size_t)blockIdx.z * M * K;
    int m0 = blockIdx.x * 32, k0 = blockIdx.y * 32;
    int tx = threadIdx.x & 31, ty = threadIdx.x >> 5;
    #pragma unroll
    for (int i = 0; i < 4; ++i)
        tile[ty + 8 * i][tx] = W[(size_t)(k0 + ty + 8 * i) * M + m0 + tx];
    __syncthreads();
    #pragma unroll
    for (int i = 0; i < 4; ++i) {
        int mm = ty + 8 * i, kk = tx;
        dst[(size_t)(m0 + mm) * K + kk + k0] = (_Float16)tile[kk][mm];
    }
}

// ============ 256x256 / BK=64 / 8-wave phase-split GEMM (R5-verified) ======
// MEASURED BEST: 146 us @ L1 (886 TF), VGPR 128 (+128 AGPR acc), 0 bank
// conflicts. FROZEN: R3-R8 schedule variants (4-phase, 2-phase, single-buf)
// all regressed; the 256-tile's 128-f32 acc register-pins this at 2 waves/EU
// (1 block/CU) and the unified VGPR+AGPR file forbids more. Tile-size A/B
// settled: L2@128^2 == L2@256^2 within noise (R2<->R3 cross-check).
// Balanced 4/4/8/8 read phases; ph4 reads NEXT tile's af(QA0) (its Ah0 unit
// landed via end-ph3 gate). Uniform vmcnt(4) at every phase end; each gate
// waits on a unit issued 3 phases (~3000cy) earlier >> 900cy HBM latency.
// LDS chunk swizzle (both-sides, m173): global chunk (c^row&7), linear dest;
// reads XOR the same key -> conflict-free ds_read_b128 (measured 0).
__global__ __launch_bounds__(512, 2) void gemm256_mfma_f16(
    const _Float16* __restrict__ A0, const _Float16* __restrict__ B0,
    const float* __restrict__ biasL, const float* __restrict__ biasR,
    int Nhalf, _Float16* __restrict__ C,
    int Mrows, int K, int N)
{
    // [dbuf][ A 256*64 | B 256*64 ] halfs = 128 KB total
    __shared__ __align__(16) _Float16 smem[2 * 32768];

    const int tid  = threadIdx.x;
    const int wave = tid >> 6;
    const int lane = tid & 63;
    const int wr = wave >> 2;      // 0..1  (M half within a quadrant)
    const int wc = wave & 3;       // 0..3  (N quarter within a quadrant)
    const int rowBase = blockIdx.y * 256;
    const int colBase = blockIdx.x * 256;

    floatx4 acc[2][2][4][2];
    #pragma unroll
    for (int qa = 0; qa < 2; ++qa)
        #pragma unroll
        for (int qb = 0; qb < 2; ++qb)
            #pragma unroll
            for (int f = 0; f < 4; ++f)
                #pragma unroll
                for (int g = 0; g < 2; ++g)
                    acc[qa][qb][f][g] = (floatx4){0.f, 0.f, 0.f, 0.f};

    // staging: wave w stages rows h*128 + w*16 .. +16 (2 calls of 8 rows).
    // lane -> row lane>>3, global chunk (lane&7)^(lane>>3), linear LDS dest.
    const int srow   = lane >> 3;
    const int schunk = ((lane & 7) ^ srow) << 3;   // halfs
    const _Float16* gA = A0 + (size_t)(rowBase + wave * 16 + srow) * K + schunk;
    const _Float16* gB = B0 + (size_t)(colBase + wave * 16 + srow) * K + schunk;
    const size_t rstep = (size_t)8 * K;
    const size_t hstep = (size_t)128 * K;

    auto stageA = [&](int b, int h, int kt) {
        _Float16* l = &smem[b * 32768 + (h * 128 + wave * 16) * 64];
        const _Float16* g = gA + (size_t)h * hstep + (size_t)kt * 64;
        gload_lds16(g, l);
        gload_lds16(g + rstep, l + 512);
    };
    auto stageB = [&](int b, int h, int kt) {
        _Float16* l = &smem[b * 32768 + 16384 + (h * 128 + wave * 16) * 64];
        const _Float16* g = gB + (size_t)h * hstep + (size_t)kt * 64;
        gload_lds16(g, l);
        gload_lds16(g + rstep, l + 512);
    };

    const int lm  = lane & 15;
    const int key = lane & 7;
    const int kg  = lane >> 4;

    half8 af0[4][2];   // A-frags QA=0 (read in PREV tile's ph4; used ph1,ph2)
    half8 af1[4][2];   // A-frags QA=1 (read ph3; used ph3,ph4)
    half8 bf0[2][2];   // B-frags QB=0 (read ph1; used ph1,ph3)
    half8 bf1[2][2];   // B-frags QB=1 (read ph2; used ph2,ph4)

    auto readA = [&](const _Float16* Ab, int QA, half8 (&af)[4][2]) {
        #pragma unroll
        for (int f = 0; f < 4; ++f)
            #pragma unroll
            for (int s = 0; s < 2; ++s) {
                int row = QA * 128 + wr * 64 + f * 16 + lm;
                int ch = (s * 4 + kg) ^ key;
                af[f][s] = *(const half8*)&Ab[row * 64 + ch * 8];
            }
    };
    auto readB = [&](const _Float16* Bb, int QB, half8 (&bf)[2][2]) {
        #pragma unroll
        for (int g = 0; g < 2; ++g)
            #pragma unroll
            for (int s = 0; s < 2; ++s) {
                int row = QB * 128 + wc * 32 + g * 16 + lm;
                int ch = (s * 4 + kg) ^ key;
                bf[g][s] = *(const half8*)&Bb[row * 64 + ch * 8];
            }
    };
    auto mfma16 = [&](half8 (&af)[4][2], half8 (&bf)[2][2], floatx4 (&ac)[4][2]) {
        __builtin_amdgcn_s_setprio(1);
        #pragma unroll
        for (int f = 0; f < 4; ++f)
            #pragma unroll
            for (int g = 0; g < 2; ++g)
                #pragma unroll
                for (int s = 0; s < 2; ++s)
                    ac[f][g] = __builtin_amdgcn_mfma_f32_16x16x32_f16(
                        af[f][s], bf[g][s], ac[f][g], 0, 0, 0);
        __builtin_amdgcn_s_setprio(0);
    };

    // prologue: stage tile 0 in steady-state age order; Ah0,Bh0 landed;
    // pre-read af0 (tile 0 QA0).
    stageA(0, 0, 0); stageB(0, 0, 0); stageB(0, 1, 0); stageA(0, 1, 0);
    vmgate<4>();
    __builtin_amdgcn_s_barrier();
    readA(&smem[0], 0, af0);

    const int nk = K >> 6;
    for (int t = 0; t < nk - 1; ++t) {
        const int b = t & 1;
        const _Float16* Ab  = &smem[b * 32768];
        const _Float16* Bb  = Ab + 16384;
        const _Float16* AbN = &smem[(b ^ 1) * 32768];
        // ph1: 4 reads (bf0) | stage Ah0' | MFMA(0,0) | gate->Bh1(t)
        readB(Bb, 0, bf0);
        stageA(b ^ 1, 0, t + 1);
        __builtin_amdgcn_s_barrier();
        mfma16(af0, bf0, acc[0][0]);
        vmgate<4>();
        __builtin_amdgcn_s_barrier();
        // ph2: 4 reads (bf1) | stage Bh0' | MFMA(0,1) | gate->Ah1(t)
        readB(Bb, 1, bf1);
        stageB(b ^ 1, 0, t + 1);
        __builtin_amdgcn_s_barrier();
        mfma16(af0, bf1, acc[0][1]);
        vmgate<4>();
        __builtin_amdgcn_s_barrier();
        // ph3: 8 reads (af1) | stage Bh1' | MFMA(1,0) | gate->Ah0'(t+1)
        readA(Ab, 1, af1);
        stageB(b ^ 1, 1, t + 1);
        __builtin_amdgcn_s_barrier();
        mfma16(af1, bf0, acc[1][0]);
        vmgate<4>();
        __builtin_amdgcn_s_barrier();
        // ph4: 8 reads (af0 of NEXT tile, Ah0' landed) | stage Ah1' |
        //      MFMA(1,1) | gate->Bh0'(t+1)
        readA(AbN, 0, af0);
        stageA(b ^ 1, 1, t + 1);
        __builtin_amdgcn_s_barrier();
        mfma16(af1, bf1, acc[1][1]);
        vmgate<4>();
        __builtin_amdgcn_s_barrier();
    }
    {   // last tile: no staging; entry outstanding = {Bh1, Ah1} (4 loads)
        const int b = (nk - 1) & 1;
        const _Float16* Ab = &smem[b * 32768];
        const _Float16* Bb = Ab + 16384;
        readB(Bb, 0, bf0);
        __builtin_amdgcn_s_barrier();
        mfma16(af0, bf0, acc[0][0]);
        vmgate<2>();                  // Bh1 landed
        __builtin_amdgcn_s_barrier();
        readB(Bb, 1, bf1);
        __builtin_amdgcn_s_barrier();
        mfma16(af0, bf1, acc[0][1]);
        vmgate<0>();                  // Ah1 landed
        __builtin_amdgcn_s_barrier();
        readA(Ab, 1, af1);
        __builtin_amdgcn_s_barrier();
        mfma16(af1, bf0, acc[1][0]);
        __builtin_amdgcn_s_barrier();
        mfma16(af1, bf1, acc[1][1]);
        __builtin_amdgcn_s_barrier();
    }

    // ---- coalesced epilogue: stage 256x256 C-tile in the dead LDS ----
    // 32B-granule XOR by (row>>2)&7: 4 lane-groups -> 4 distinct bank
    // quadrants; bijective per row.
    _Float16* Ct = smem;
    const int cq = (lane >> 4) * 4;
    #pragma unroll
    for (int qb = 0; qb < 2; ++qb)
        #pragma unroll
        for (int g = 0; g < 2; ++g) {
            int col = qb * 128 + wc * 32 + g * 16 + lm;
            int gcol = colBase + col;
            float bv = (gcol < Nhalf) ? biasL[gcol] : biasR[gcol - Nhalf];
            #pragma unroll
            for (int qa = 0; qa < 2; ++qa)
                #pragma unroll
                for (int f = 0; f < 4; ++f)
                    #pragma unroll
                    for (int r = 0; r < 4; ++r) {
                        int row = qa * 128 + wr * 64 + f * 16 + cq + r;
                        int gi = (col >> 4) ^ ((row >> 2) & 7);
                        Ct[row * 256 + gi * 16 + (col & 15)] =
                            (_Float16)(acc[qa][qb][f][g][r] + bv);
                    }
        }
    __syncthreads();
    // 512 threads store 16 rows/pass (row = 512B contiguous), 16 passes
    const int r0 = tid >> 5;           // 0..15
    const int cc = (tid & 31) * 8;     // halfs within row
    const int gg = cc >> 4;
    #pragma unroll
    for (int ps = 0; ps < 16; ++ps) {
        int row = ps * 16 + r0;
        int grow = rowBase + row;
        if (grow < Mrows) {
            int gp = gg ^ ((row >> 2) & 7);
            half8 v = *(const half8*)&Ct[row * 256 + gp * 16 + (cc & 15)];
            *(half8*)&C[(size_t)grow * N + colBase + cc] = v;
        }
    }
}

// ---------------- 128x128 MFMA GEMM (proven R2 kernel; layer-3) ------------
__global__ __launch_bounds__(256) void gemm_mfma_f16(
    const _Float16* __restrict__ A0, const _Float16* __restrict__ B0,
    const float* __restrict__ biasL, const float* __restrict__ biasR,
    int Nhalf, _Float16* __restrict__ C,
    int Mrows, int K, int N)
{
    __shared__ __align__(16) _Float16 smem[2 * 2 * 128 * 32];
    _Float16* As = smem;
    _Float16* Bs = smem + 2 * 128 * 32;

    const int tid = threadIdx.x;
    const int wave = tid >> 6;
    const int lane = tid & 63;
    const int wm = (wave >> 1) * 64;
    const int wn = (wave & 1) * 64;
    const int lm = lane & 15;
    const int swz = (((lane >> 4) ^ ((lane >> 1) & 3)) << 3);

    const int rowBase = blockIdx.y * 128;
    const int colBase = blockIdx.x * 128;

    floatx4 acc[4][4];
    #pragma unroll
    for (int i = 0; i < 4; ++i)
        #pragma unroll
        for (int j = 0; j < 4; ++j)
            acc[i][j] = (floatx4){0.f, 0.f, 0.f, 0.f};

    const int sr = lane >> 2;
    const int scol = (((lane & 3) ^ ((lane >> 3) & 3)) << 3);
    const _Float16* gA = A0 + (size_t)(rowBase + wave * 32 + sr) * K + scol;
    const _Float16* gB = B0 + (size_t)(colBase + wave * 32 + sr) * K + scol;
    const size_t skip16 = (size_t)16 * K;
    const int lo0 = (wave * 32) * 32;
    const int lo1 = (wave * 32 + 16) * 32;

    gload_lds16(gA, &As[lo0]);
    gload_lds16(gA + skip16, &As[lo1]);
    gload_lds16(gB, &Bs[lo0]);
    gload_lds16(gB + skip16, &Bs[lo1]);
    __syncthreads();

    const int nk = K >> 5;
    for (int t = 0; t < nk; ++t) {
        const int p = t & 1;
        const int po = p * 128 * 32;
        if (t + 1 < nk) {
            const int k1 = (t + 1) << 5;
            const int qo = (p ^ 1) * 128 * 32;
            gload_lds16(gA + k1, &As[qo + lo0]);
            gload_lds16(gA + skip16 + k1, &As[qo + lo1]);
            gload_lds16(gB + k1, &Bs[qo + lo0]);
            gload_lds16(gB + skip16 + k1, &Bs[qo + lo1]);
        }
        half8 a0[4], b0[4];
        #pragma unroll
        for (int i = 0; i < 4; ++i) {
            a0[i] = *(const half8*)&As[po + (wm + i * 16 + lm) * 32 + swz];
            b0[i] = *(const half8*)&Bs[po + (wn + i * 16 + lm) * 32 + swz];
        }
        #pragma unroll
        for (int i = 0; i < 4; ++i)
            #pragma unroll
            for (int j = 0; j < 4; ++j)
                acc[i][j] = __builtin_amdgcn_mfma_f32_16x16x32_f16(a0[i], b0[j], acc[i][j], 0, 0, 0);
        __syncthreads();
    }

    _Float16* Ct = smem;
    const int cq = (lane >> 4) * 4;
    #pragma unroll
    for (int j = 0; j < 4; ++j) {
        int col = wn + j * 16 + lm;
        int gcol = colBase + col;
        float bv = (gcol < Nhalf) ? biasL[gcol] : biasR[gcol - Nhalf];
        #pragma unroll
        for (int i = 0; i < 4; ++i) {
            int row = wm + i * 16 + cq;
            #pragma unroll
            for (int r = 0; r < 4; ++r) {
                int rr = row + r;
                Ct[rr * 128 + (col ^ (((rr >> 2) & 7) << 4))] = (_Float16)(acc[i][j][r] + bv);
            }
        }
    }
    __syncthreads();
    const int r0 = tid >> 4;
    const int cc = (tid & 15) * 8;
    #pragma unroll
    for (int ps = 0; ps < 8; ++ps) {
        int row = ps * 16 + r0;
        int grow = rowBase + row;
        if (grow < Mrows) {
            half8 v = *(const half8*)&Ct[row * 128 + (cc ^ (((row >> 2) & 7) << 4))];
            *(half8*)&C[(size_t)grow * N + colBase + cc] = v;
        }
    }
}

// ---------------- CSR build ----------------

// fused: edge arrays + cnt zero + gstart/gend zero + hpool zero (one pass;
// stream order guarantees hpool is zeroed long before k_pool_acc runs)
__global__ void k_build_zero(const int* __restrict__ ei, int* __restrict__ src,
                             int* __restrict__ dst, int* __restrict__ cnt,
                             int* __restrict__ gstart, float* __restrict__ hpool) {
    int i = blockIdx.x * 256 + threadIdx.x;
    if (i < NE) { src[i] = ei[i]; dst[i] = ei[NE + i]; }
    else if (i < NEE) { src[i] = i - NE; dst[i] = i - NE; }
    if (i < NN) cnt[i] = 0;
    if (i < 2 * NG) gstart[i] = 0;
    if (i < NG * 256) hpool[i] = 0.f;
}

__global__ void k_count(const int* __restrict__ dst, int* __restrict__ cnt) {
    int i = blockIdx.x * 256 + threadIdx.x;
    if (i < NEE) atomicAdd(&cnt[dst[i]], 1);
}

__global__ __launch_bounds__(256) void k_scan(const int* __restrict__ cnt,
                                              int* __restrict__ off, int* __restrict__ cur) {
    __shared__ int partial[256];
    __shared__ int ppre[257];
    int t = threadIdx.x;
    const int chunk = (NN + 255) / 256;
    int lo = t * chunk, hi = min(NN, (t + 1) * chunk);
    int s = 0;
    for (int i = lo; i < hi; ++i) s += cnt[i];
    partial[t] = s;
    __syncthreads();
    if (t == 0) {
        int acc = 0;
        for (int i = 0; i < 256; ++i) { ppre[i] = acc; acc += partial[i]; }
        ppre[256] = acc;
    }
    __syncthreads();
    int acc = ppre[t];
    for (int i = lo; i < hi; ++i) { off[i] = acc; cur[i] = acc; acc += cnt[i]; }
    if (t == 0) off[NN] = ppre[256];
}

__global__ void k_fill(const int* __restrict__ src, const int* __restrict__ dst,
                       int* __restrict__ cur, int* __restrict__ slist) {
    int e = blockIdx.x * 256 + threadIdx.x;
    if (e < NEE) { int p = atomicAdd(&cur[dst[e]], 1); slist[p] = src[e]; }
}

// ---------------- fused GATv2 edge pipeline (fp16 activations) -------------
// xlr is the fused GEMM output: row n = [xl(n) | xr(n)], stride LD = 2*NH*C.
// depth-2 prefetch (3 buffers): hides slist scalar-load + row gather latency.
// R10: att in fp16 (half traffic), __expf (arg <= 0, output is fp16 anyway).
template<int C>
__global__ __launch_bounds__(256) void k_gat_fused(
    const _Float16* __restrict__ xlr, const _Float16* __restrict__ att,
    const int* __restrict__ eoff, const int* __restrict__ slist,
    const float* __restrict__ bias, _Float16* __restrict__ out)
{
    constexpr int LD = 2 * NH * C;          // fused GEMM row stride (halfs)
    constexpr int CH = (C >= 512) ? 8 : 4;  // halfs per load per lane
    constexpr int NC = C / (64 * CH);       // chunks per head-row
    constexpr int PL = NC * CH;             // elems per lane
    __shared__ float red[NH * C];
    const int n = blockIdx.x;
    const int h = threadIdx.x >> 6;
    const int lane = threadIdx.x & 63;

    float xrv[PL], attv[PL], acc[PL];
    {
        const _Float16* xrrow = xlr + (size_t)n * LD + NH * C + h * C + lane * CH;
        const _Float16* ah = att + h * C + lane * CH;
        #pragma unroll
        for (int c = 0; c < NC; ++c) {
            if constexpr (CH == 8) {
                half8 hv = *(const half8*)(xrrow + c * 64 * CH);
                half8 av = *(const half8*)(ah + c * 64 * CH);
                #pragma unroll
                for (int e = 0; e < 8; ++e) {
                    xrv[c * 8 + e] = (float)hv[e];
                    attv[c * 8 + e] = (float)av[e];
                }
            } else {
                half4 hv = *(const half4*)(xrrow + c * 64 * CH);
                half4 av = *(const half4*)(ah + c * 64 * CH);
                #pragma unroll
                for (int e = 0; e < 4; ++e) {
                    xrv[c * 4 + e] = (float)hv[e];
                    attv[c * 4 + e] = (float)av[e];
                }
            }
        }
        #pragma unroll
        for (int e = 0; e < PL; ++e) acc[e] = 0.f;
    }

    float m = -INFINITY, den = 0.f;
    const int start = eoff[n], end = eoff[n + 1];

    _Float16 bufA[PL], bufB[PL], bufC[PL];
    auto ldrow = [&](int s, _Float16* buf) {
        const _Float16* p = xlr + (size_t)s * LD + h * C + lane * CH;
        #pragma unroll
        for (int c = 0; c < NC; ++c) {
            if constexpr (CH == 8)
                *(half8*)&buf[c * 8] = *(const half8*)(p + c * 64 * CH);
            else
                *(half4*)&buf[c * 4] = *(const half4*)(p + c * 64 * CH);
        }
    };

    if (start < end) ldrow(slist[start], bufA);
    if (start + 1 < end) ldrow(slist[start + 1], bufB);
    for (int j = start; j < end; ++j) {
        if (j + 2 < end) ldrow(slist[j + 2], bufC);   // depth-2 prefetch
        float xv[PL];
        float ps = 0.f;
        #pragma unroll
        for (int e = 0; e < PL; ++e) {
            xv[e] = (float)bufA[e];
            float v = xv[e] + xrv[e];
            v = v > 0.f ? v : 0.2f * v;
            ps = fmaf(v, attv[e], ps);
        }
        ps = waveSum(ps);
        float m_new = fmaxf(m, ps);
        float scale = __expf(m - m_new);
        float ex = __expf(ps - m_new);
        den = den * scale + ex;
        m = m_new;
        #pragma unroll
        for (int e = 0; e < PL; ++e)
            acc[e] = fmaf(ex, xv[e], acc[e] * scale);
        #pragma unroll
        for (int e = 0; e < PL; ++e) { bufA[e] = bufB[e]; bufB[e] = bufC[e]; }
    }

    float inv = 1.f / (den + 1e-16f);
    #pragma unroll
    for (int c = 0; c < NC; ++c) {
        int off = h * C + c * 64 * CH + lane * CH;
        #pragma unroll
        for (int e = 0; e < CH; e += 4) {
            float4 r;
            r.x = acc[c * CH + e + 0] * inv;
            r.y = acc[c * CH + e + 1] * inv;
            r.z = acc[c * CH + e + 2] * inv;
            r.w = acc[c * CH + e + 3] * inv;
            *(float4*)&red[off + e] = r;
        }
    }
    __syncthreads();

    int t = threadIdx.x;
    for (int c4 = t; c4 < C / 4; c4 += 256) {
        int c = c4 * 4;
        float4 r0 = *(const float4*)&red[0 * C + c];
        float4 r1 = *(const float4*)&red[1 * C + c];
        float4 r2 = *(const float4*)&red[2 * C + c];
        float4 r3 = *(const float4*)&red[3 * C + c];
        float4 bv = *(const float4*)(bias + c);
        half4 o;
        o[0] = (_Float16)fmaxf((r0.x + r1.x + r2.x + r3.x) * 0.25f + bv.x, 0.f);
        o[1] = (_Float16)fmaxf((r0.y + r1.y + r2.y + r3.y) * 0.25f + bv.y, 0.f);
        o[2] = (_Float16)fmaxf((r0.z + r1.z + r2.z + r3.z) * 0.25f + bv.z, 0.f);
        o[3] = (_Float16)fmaxf((r0.w + r1.w + r2.w + r3.w) * 0.25f + bv.w, 0.f);
        *(half4*)(out + (size_t)n * C + c) = o;
    }
}

// ---------------- gate + pool + MLP ----------------

__global__ __launch_bounds__(128) void k_gate(
    const _Float16* __restrict__ x, const float* __restrict__ Wg0,
    const float* __restrict__ bg0, const float* __restrict__ Wg1,
    const float* __restrict__ bg1, float* __restrict__ g)
{
    int n = blockIdx.x;
    int t = threadIdx.x;
    __shared__ float xs[256];
    __shared__ float wsum[2];
    const _Float16* xp = x + (size_t)n * 256;
    xs[t] = (float)xp[t]; xs[t + 128] = (float)xp[t + 128];
    __syncthreads();
    float acc = bg0[t];
    for (int k = 0; k < 256; ++k) acc = fmaf(xs[k], Wg0[k * 128 + t], acc);
    acc = acc > 0.f ? acc : 0.f;
    float prod = acc * Wg1[t];
    prod = waveSum(prod);
    if ((t & 63) == 0) wsum[t >> 6] = prod;
    __syncthreads();
    if (t == 0) g[n] = wsum[0] + wsum[1] + bg1[0];
}

__global__ void k_group_bounds(const int* __restrict__ batch, int* __restrict__ gstart,
                               int* __restrict__ gend) {
    int n = blockIdx.x * 256 + threadIdx.x;
    if (n >= NN) return;
    int b = batch[n];
    if (n == 0 || batch[n - 1] != b) gstart[b] = n;
    if (n == NN - 1 || batch[n + 1] != b) gend[b] = n + 1;
}

// per-group softmax stats: m[g], invden[g]
__global__ __launch_bounds__(256) void k_pool_stats(
    const float* __restrict__ g, const int* __restrict__ gstart,
    const int* __restrict__ gend, float* __restrict__ mOut,
    float* __restrict__ invdenOut)
{
    int gi = blockIdx.x;
    int t = threadIdx.x;
    int s0 = gstart[gi], e0 = gend[gi];
    __shared__ float red[4];
    float mx = -1e30f;
    for (int n = s0 + t; n < e0; n += 256) mx = fmaxf(mx, g[n]);
    float wm = waveMax(mx);
    if ((t & 63) == 0) red[t >> 6] = wm;
    __syncthreads();
    float m = fmaxf(fmaxf(red[0], red[1]), fmaxf(red[2], red[3]));
    __syncthreads();
    float sm = 0.f;
    for (int n = s0 + t; n < e0; n += 256) sm += expf(g[n] - m);
    sm = waveSum(sm);
    if ((t & 63) == 0) red[t >> 6] = sm;
    __syncthreads();
    if (t == 0) {
        float den = red[0] + red[1] + red[2] + red[3] + 1e-16f;
        mOut[gi] = m;
        invdenOut[gi] = 1.f / den;
    }
}

#define PCH 16
__global__ __launch_bounds__(256) void k_pool_acc(
    const _Float16* __restrict__ x, const float* __restrict__ g,
    const int* __restrict__ batch, const float* __restrict__ m,
    const float* __restrict__ invden, float* __restrict__ hpool)
{
    int base = blockIdx.x * PCH;
    int t = threadIdx.x;
    float acc = 0.f;
    int cur = -1;
    for (int i = 0; i < PCH; ++i) {
        int n = base + i;
        if (n >= NN) break;
        int b = batch[n];
        if (b != cur) {
            if (cur >= 0) atomicAdd(&hpool[cur * 256 + t], acc);
            cur = b; acc = 0.f;
        }
        float w = expf(g[n] - m[b]) * invden[b];
        acc = fmaf(w, (float)x[(size_t)n * 256 + t], acc);
    }
    if (cur >= 0) atomicAdd(&hpool[cur * 256 + t], acc);
}

__global__ __launch_bounds__(256) void k_mlp(
    const float* __restrict__ hpool,
    const float* __restrict__ Wm0, const float* __restrict__ bm0,
    const float* __restrict__ Wm1, const float* __restrict__ bm1,
    const float* __restrict__ Wm2, const float* __restrict__ bm2,
    const float* __restrict__ Wm3, const float* __restrict__ bm3,
    const float* __restrict__ Wm4, const float* __restrict__ bm4,
    float* __restrict__ out)
{
    __shared__ float bufA[8 * 256];
    __shared__ float bufB[8 * 128];
    int t = threadIdx.x;
    for (int i = t; i < 8 * 256; i += 256) bufA[i] = hpool[i];
    __syncthreads();
    for (int i = t; i < 8 * 128; i += 256) {
        int r = i >> 7, c = i & 127;
        float acc = bm0[c];
        for (int k = 0; k < 256; ++k) acc = fmaf(bufA[r * 256 + k], Wm0[k * 128 + c], acc);
        bufB[i] = fmaxf(acc, 0.f);
    }
    __syncthreads();
    for (int i = t; i < 8 * 64; i += 256) {
        int r = i >> 6, c = i & 63;
        float acc = bm1[c];
        for (int k = 0; k < 128; ++k) acc = fmaf(bufB[r * 128 + k], Wm1[k * 64 + c], acc);
        bufA[i] = fmaxf(acc, 0.f);
    }
    __syncthreads();
    for (int i = t; i < 8 * 32; i += 256) {
        int r = i >> 5, c = i & 31;
        float acc = bm2[c];
        for (int k = 0; k < 64; ++k) acc = fmaf(bufA[r * 64 + k], Wm2[k * 32 + c], acc);
        bufB[i] = fmaxf(acc, 0.f);
    }
    __syncthreads();
    for (int i = t; i < 8 * 16; i += 256) {
        int r = i >> 4, c = i & 15;
        float acc = bm3[c];
        for (int k = 0; k < 32; ++k) acc = fmaf(bufB[r * 32 + k], Wm3[k * 16 + c], acc);
        bufA[i] = fmaxf(acc, 0.f);
    }
    __syncthreads();
    if (t < 8) {
        float acc = bm4[0];
        for (int k = 0; k < 16; ++k) acc = fmaf(bufA[t * 16 + k], Wm4[k], acc);
        out[t] = acc;
    }
}

// ---------------- host orchestration ----------------

static void run_gat_layer(const _Float16* ain, int K, int C,
                          const float* Wl, const float* bl,
                          const float* Wr, const float* br,
                          const _Float16* attH, const float* bias,
                          _Float16* wb0, _Float16* xlr,
                          const int* eoff, const int* slist,
                          _Float16* xout, hipStream_t stream)
{
    int HC = NH * C;
    dim3 tgrid(HC / 32, K / 32, 2);
    k_cvtWT2<<<tgrid, 256, 0, stream>>>(Wl, Wr, wb0, K, HC);
    // fused Wl/Wr GEMM: N = 2*HC, output row n = [xl(n) | xr(n)]
    if (C >= 512) {
        dim3 ggrid(2 * HC / 256, NNP / 256);
        gemm256_mfma_f16<<<ggrid, 512, 0, stream>>>(ain, wb0, bl, br, HC, xlr, NN, K, 2 * HC);
    } else {
        dim3 ggrid(2 * HC / 128, NNP / 128);
        gemm_mfma_f16<<<ggrid, 256, 0, stream>>>(ain, wb0, bl, br, HC, xlr, NN, K, 2 * HC);
    }

    if (C == 1024)
        k_gat_fused<1024><<<NN, 256, 0, stream>>>(xlr, attH, eoff, slist, bias, xout);
    else if (C == 512)
        k_gat_fused<512><<<NN, 256, 0, stream>>>(xlr, attH, eoff, slist, bias, xout);
    else
        k_gat_fused<256><<<NN, 256, 0, stream>>>(xlr, attH, eoff, slist, bias, xout);
}

extern "C" void kernel_launch(void* const* d_in, const int* in_sizes, int n_in,
                              void* d_out, int out_size, void* d_ws, size_t ws_size,
                              hipStream_t stream) {
    const float* x      = (const float*)d_in[0];
    const int* ei       = (const int*)d_in[1];
    const int* batch    = (const int*)d_in[2];
    const float* Wl1 = (const float*)d_in[3];  const float* bl1 = (const float*)d_in[4];
    const float* Wr1 = (const float*)d_in[5];  const float* br1 = (const float*)d_in[6];
    const float* att1= (const float*)d_in[7];  const float* b1  = (const float*)d_in[8];
    const float* Wl2 = (const float*)d_in[9];  const float* bl2 = (const float*)d_in[10];
    const float* Wr2 = (const float*)d_in[11]; const float* br2 = (const float*)d_in[12];
    const float* att2= (const float*)d_in[13]; const float* b2  = (const float*)d_in[14];
    const float* Wl3 = (const float*)d_in[15]; const float* bl3 = (const float*)d_in[16];
    const float* Wr3 = (const float*)d_in[17]; const float* br3 = (const float*)d_in[18];
    const float* att3= (const float*)d_in[19]; const float* b3  = (const float*)d_in[20];
    const float* Wm0 = (const float*)d_in[21]; const float* bm0 = (const float*)d_in[22];
    const float* Wm1 = (const float*)d_in[23]; const float* bm1 = (const float*)d_in[24];
    const float* Wm2 = (const float*)d_in[25]; const float* bm2 = (const float*)d_in[26];
    const float* Wm3 = (const float*)d_in[27]; const float* bm3 = (const float*)d_in[28];
    const float* Wm4 = (const float*)d_in[29]; const float* bm4 = (const float*)d_in[30];
    const float* Wg0 = (const float*)d_in[31]; const float* bg0 = (const float*)d_in[32];
    const float* Wg1 = (const float*)d_in[33]; const float* bg1 = (const float*)d_in[34];
    float* out = (float*)d_out;

    // workspace carve (float units = 4B); fp16 buffers 16B-aligned, padded rows
    float* ws = (float*)d_ws;
    size_t o = 0;
    _Float16* xlr = (_Float16*)(ws + o); o += (size_t)NNP * 8192 / 2;  // fused [xl|xr], layer1 sized
    _Float16* x1  = (_Float16*)(ws + o); o += (size_t)NNP * 1024 / 2;
    _Float16* x2  = (_Float16*)(ws + o); o += (size_t)NNP * 512 / 2;
    _Float16* x3  = (_Float16*)(ws + o); o += (size_t)NNP * 256 / 2;
    _Float16* a0p = (_Float16*)(ws + o); o += (size_t)NNP * 1536 / 2;
    _Float16* wb0 = (_Float16*)(ws + o); o += (size_t)8192 * 1536 / 2; // [WlT | WrT], layer1 sized
    _Float16* attH= (_Float16*)(ws + o); o += 8192 / 2;                // [att1|att2|att3] fp16
    int* srcA    = (int*)(ws + o); o += NEE;
    int* dstA    = (int*)(ws + o); o += NEE;
    int* cnt     = (int*)(ws + o); o += NN;
    int* eoff    = (int*)(ws + o); o += NN + 1;
    int* cur     = (int*)(ws + o); o += NN;
    int* slist   = (int*)(ws + o); o += NEE;
    float* g     = ws + o; o += NN;
    int* gstart  = (int*)(ws + o); o += NG;
    int* gend    = (int*)(ws + o); o += NG;
    float* gm    = ws + o; o += NG;
    float* ginv  = ws + o; o += NG;
    float* hpool = ws + o; o += NG * 256;

    // build CSR by dst (slist holds src node ids) + all zeroing in one pass
    int ebB = (NEE + 255) / 256;
    k_build_zero<<<ebB, 256, 0, stream>>>(ei, srcA, dstA, cnt, gstart, hpool);
    k_count<<<ebB, 256, 0, stream>>>(dstA, cnt);
    k_scan<<<1, 256, 0, stream>>>(cnt, eoff, cur);
    k_fill<<<ebB, 256, 0, stream>>>(srcA, dstA, cur, slist);

    // att -> fp16 (once, all three layers)
    k_cvt_att3<<<28, 256, 0, stream>>>(att1, att2, att3, attH);

    // layer-1 input -> fp16 (only conversion needed; later layers emit fp16)
    int nA = NN * 1536;
    k_cvtA<<<(nA + 255) / 256, 256, 0, stream>>>(x, a0p, nA);

    // three GATv2 layers
    run_gat_layer(a0p, 1536, 1024, Wl1, bl1, Wr1, br1, attH, b1,
                  wb0, xlr, eoff, slist, x1, stream);
    run_gat_layer(x1,  1024, 512,  Wl2, bl2, Wr2, br2, attH + 4096, b2,
                  wb0, xlr, eoff, slist, x2, stream);
    run_gat_layer(x2,  512,  256,  Wl3, bl3, Wr3, br3, attH + 6144, b3,
                  wb0, xlr, eoff, slist, x3, stream);

    // gate + pool + MLP
    k_gate<<<NN, 128, 0, stream>>>(x3, Wg0, bg0, Wg1, bg1, g);
    k_group_bounds<<<(NN + 255) / 256, 256, 0, stream>>>(batch, gstart, gend);
    k_pool_stats<<<NG, 256, 0, stream>>>(g, gstart, gend, gm, ginv);
    k_pool_acc<<<(NN + PCH - 1) / PCH, 256, 0, stream>>>(x3, g, batch, gm, ginv, hpool);
    k_mlp<<<1, 256, 0, stream>>>(hpool, Wm0, bm0, Wm1, bm1, Wm2, bm2,
                                 Wm3, bm3, Wm4, bm4, out);
}

// Round 11
// 624.856 us; speedup vs baseline: 4.2527x; 1.0178x over previous
//
#include <hip/hip_runtime.h>
#include <math.h>

// Problem constants (from reference)
#define NN 5000
#define NNP 5120    // padded rows for GEMM A-operand OOB staging
#define NE 50000
#define NEE 55000   // edges + self loops
#define NG 8
#define NH 4

typedef __attribute__((ext_vector_type(8))) _Float16 half8;
typedef __attribute__((ext_vector_type(4))) _Float16 half4;
typedef __attribute__((ext_vector_type(4))) float floatx4;

// ---------------- utility device functions ----------------

__device__ inline float waveSum(float v) {
    #pragma unroll
    for (int o = 32; o > 0; o >>= 1) v += __shfl_xor(v, o, 64);
    return v;
}
// three independent reductions, shfl chains interleaved at source level so
// the ~30cy DS latencies overlap (3 edges reduced in ~1.3x the time of one)
__device__ inline void waveSum3(float& a, float& b, float& c) {
    #pragma unroll
    for (int o = 32; o > 0; o >>= 1) {
        float ta = __shfl_xor(a, o, 64);
        float tb = __shfl_xor(b, o, 64);
        float tc = __shfl_xor(c, o, 64);
        a += ta; b += tb; c += tc;
    }
}
__device__ inline float waveMax(float v) {
    #pragma unroll
    for (int o = 32; o > 0; o >>= 1) v = fmaxf(v, __shfl_xor(v, o, 64));
    return v;
}

// async global->LDS DMA, 16B per lane; lds dest is wave-uniform base + lane*16
__device__ __forceinline__ void gload_lds16(const _Float16* g, _Float16* l) {
    __builtin_amdgcn_global_load_lds(
        (__attribute__((address_space(1))) void*)g,
        (__attribute__((address_space(3))) void*)l,
        16, 0, 0);
}

template<int N>
__device__ __forceinline__ void vmgate() {
    if constexpr (N == 0) asm volatile("s_waitcnt vmcnt(0)" ::: "memory");
    else if constexpr (N == 2) asm volatile("s_waitcnt vmcnt(2)" ::: "memory");
    else if constexpr (N == 4) asm volatile("s_waitcnt vmcnt(4)" ::: "memory");
    // N < 0: no gate
}

// ---------------- fp32 -> fp16 conversion ----------------

__global__ void k_cvtA(const float* __restrict__ X, _Float16* __restrict__ A0, int n) {
    int i = blockIdx.x * 256 + threadIdx.x;
    if (i >= n) return;
    A0[i] = (_Float16)X[i];
}

// att1/att2/att3 (fp32) -> packed fp16 [4096 | 2048 | 1024] halfs.
__global__ void k_cvt_att3(const float* __restrict__ a1, const float* __restrict__ a2,
                           const float* __restrict__ a3, _Float16* __restrict__ d) {
    int i = blockIdx.x * 256 + threadIdx.x;
    if (i < 4096) d[i] = (_Float16)a1[i];
    else if (i < 6144) d[i] = (_Float16)a2[i - 4096];
    else if (i < 7168) d[i] = (_Float16)a3[i - 6144];
}

// Wl and Wr (K x M fp32) -> B0 fp16 TRANSPOSED: [WlT | WrT] each (M x K).
__global__ __launch_bounds__(256) void k_cvtWT2(const float* __restrict__ Wl,
        const float* __restrict__ Wr, _Float16* __restrict__ B0, int K, int M)
{
    __shared__ float tile[32][33];
    const float* W = blockIdx.z ? Wr : Wl;
    _Float16* dst = B0 + (size_t)blockIdx.z * M * K;
    int m0 = blockIdx.x * 32, k0 = blockIdx.y * 32;
    int tx = threadIdx.x & 31, ty = threadIdx.x >> 5;
    #pragma unroll
    for (int i = 0; i < 4; ++i)
        tile[ty + 8 * i][tx] = W[(size_t)(k0 + ty + 8 * i) * M + m0 + tx];
    __syncthreads();
    #pragma unroll
    for (int i = 0; i < 4; ++i) {
        int mm = ty + 8 * i, kk = tx;
        dst[(size_t)(m0 + mm) * K + kk + k0] = (_Float16)tile[kk][mm];
    }
}

// ============ 256x256 / BK=64 / 8-wave phase-split GEMM (R5-verified) ======
// MEASURED BEST: 146 us @ L1 (886 TF), VGPR 128 (+128 AGPR acc), 0 bank
// conflicts. FROZEN (R3-R8 settled: schedule variants and occupancy pushes
// all regress; the 128-f32 acc pins this at 2 waves/EU).
__global__ __launch_bounds__(512, 2) void gemm256_mfma_f16(
    const _Float16* __restrict__ A0, const _Float16* __restrict__ B0,
    const float* __restrict__ biasL, const float* __restrict__ biasR,
    int Nhalf, _Float16* __restrict__ C,
    int Mrows, int K, int N)
{
    // [dbuf][ A 256*64 | B 256*64 ] halfs = 128 KB total
    __shared__ __align__(16) _Float16 smem[2 * 32768];

    const int tid  = threadIdx.x;
    const int wave = tid >> 6;
    const int lane = tid & 63;
    const int wr = wave >> 2;      // 0..1  (M half within a quadrant)
    const int wc = wave & 3;       // 0..3  (N quarter within a quadrant)
    const int rowBase = blockIdx.y * 256;
    const int colBase = blockIdx.x * 256;

    floatx4 acc[2][2][4][2];
    #pragma unroll
    for (int qa = 0; qa < 2; ++qa)
        #pragma unroll
        for (int qb = 0; qb < 2; ++qb)
            #pragma unroll
            for (int f = 0; f < 4; ++f)
                #pragma unroll
                for (int g = 0; g < 2; ++g)
                    acc[qa][qb][f][g] = (floatx4){0.f, 0.f, 0.f, 0.f};

    const int srow   = lane >> 3;
    const int schunk = ((lane & 7) ^ srow) << 3;   // halfs
    const _Float16* gA = A0 + (size_t)(rowBase + wave * 16 + srow) * K + schunk;
    const _Float16* gB = B0 + (size_t)(colBase + wave * 16 + srow) * K + schunk;
    const size_t rstep = (size_t)8 * K;
    const size_t hstep = (size_t)128 * K;

    auto stageA = [&](int b, int h, int kt) {
        _Float16* l = &smem[b * 32768 + (h * 128 + wave * 16) * 64];
        const _Float16* g = gA + (size_t)h * hstep + (size_t)kt * 64;
        gload_lds16(g, l);
        gload_lds16(g + rstep, l + 512);
    };
    auto stageB = [&](int b, int h, int kt) {
        _Float16* l = &smem[b * 32768 + 16384 + (h * 128 + wave * 16) * 64];
        const _Float16* g = gB + (size_t)h * hstep + (size_t)kt * 64;
        gload_lds16(g, l);
        gload_lds16(g + rstep, l + 512);
    };

    const int lm  = lane & 15;
    const int key = lane & 7;
    const int kg  = lane >> 4;

    half8 af0[4][2];   // A-frags QA=0 (read in PREV tile's ph4; used ph1,ph2)
    half8 af1[4][2];   // A-frags QA=1 (read ph3; used ph3,ph4)
    half8 bf0[2][2];   // B-frags QB=0 (read ph1; used ph1,ph3)
    half8 bf1[2][2];   // B-frags QB=1 (read ph2; used ph2,ph4)

    auto readA = [&](const _Float16* Ab, int QA, half8 (&af)[4][2]) {
        #pragma unroll
        for (int f = 0; f < 4; ++f)
            #pragma unroll
            for (int s = 0; s < 2; ++s) {
                int row = QA * 128 + wr * 64 + f * 16 + lm;
                int ch = (s * 4 + kg) ^ key;
                af[f][s] = *(const half8*)&Ab[row * 64 + ch * 8];
            }
    };
    auto readB = [&](const _Float16* Bb, int QB, half8 (&bf)[2][2]) {
        #pragma unroll
        for (int g = 0; g < 2; ++g)
            #pragma unroll
            for (int s = 0; s < 2; ++s) {
                int row = QB * 128 + wc * 32 + g * 16 + lm;
                int ch = (s * 4 + kg) ^ key;
                bf[g][s] = *(const half8*)&Bb[row * 64 + ch * 8];
            }
    };
    auto mfma16 = [&](half8 (&af)[4][2], half8 (&bf)[2][2], floatx4 (&ac)[4][2]) {
        __builtin_amdgcn_s_setprio(1);
        #pragma unroll
        for (int f = 0; f < 4; ++f)
            #pragma unroll
            for (int g = 0; g < 2; ++g)
                #pragma unroll
                for (int s = 0; s < 2; ++s)
                    ac[f][g] = __builtin_amdgcn_mfma_f32_16x16x32_f16(
                        af[f][s], bf[g][s], ac[f][g], 0, 0, 0);
        __builtin_amdgcn_s_setprio(0);
    };

    stageA(0, 0, 0); stageB(0, 0, 0); stageB(0, 1, 0); stageA(0, 1, 0);
    vmgate<4>();
    __builtin_amdgcn_s_barrier();
    readA(&smem[0], 0, af0);

    const int nk = K >> 6;
    for (int t = 0; t < nk - 1; ++t) {
        const int b = t & 1;
        const _Float16* Ab  = &smem[b * 32768];
        const _Float16* Bb  = Ab + 16384;
        const _Float16* AbN = &smem[(b ^ 1) * 32768];
        readB(Bb, 0, bf0);
        stageA(b ^ 1, 0, t + 1);
        __builtin_amdgcn_s_barrier();
        mfma16(af0, bf0, acc[0][0]);
        vmgate<4>();
        __builtin_amdgcn_s_barrier();
        readB(Bb, 1, bf1);
        stageB(b ^ 1, 0, t + 1);
        __builtin_amdgcn_s_barrier();
        mfma16(af0, bf1, acc[0][1]);
        vmgate<4>();
        __builtin_amdgcn_s_barrier();
        readA(Ab, 1, af1);
        stageB(b ^ 1, 1, t + 1);
        __builtin_amdgcn_s_barrier();
        mfma16(af1, bf0, acc[1][0]);
        vmgate<4>();
        __builtin_amdgcn_s_barrier();
        readA(AbN, 0, af0);
        stageA(b ^ 1, 1, t + 1);
        __builtin_amdgcn_s_barrier();
        mfma16(af1, bf1, acc[1][1]);
        vmgate<4>();
        __builtin_amdgcn_s_barrier();
    }
    {   // last tile
        const int b = (nk - 1) & 1;
        const _Float16* Ab = &smem[b * 32768];
        const _Float16* Bb = Ab + 16384;
        readB(Bb, 0, bf0);
        __builtin_amdgcn_s_barrier();
        mfma16(af0, bf0, acc[0][0]);
        vmgate<2>();
        __builtin_amdgcn_s_barrier();
        readB(Bb, 1, bf1);
        __builtin_amdgcn_s_barrier();
        mfma16(af0, bf1, acc[0][1]);
        vmgate<0>();
        __builtin_amdgcn_s_barrier();
        readA(Ab, 1, af1);
        __builtin_amdgcn_s_barrier();
        mfma16(af1, bf0, acc[1][0]);
        __builtin_amdgcn_s_barrier();
        mfma16(af1, bf1, acc[1][1]);
        __builtin_amdgcn_s_barrier();
    }

    // ---- coalesced epilogue ----
    _Float16* Ct = smem;
    const int cq = (lane >> 4) * 4;
    #pragma unroll
    for (int qb = 0; qb < 2; ++qb)
        #pragma unroll
        for (int g = 0; g < 2; ++g) {
            int col = qb * 128 + wc * 32 + g * 16 + lm;
            int gcol = colBase + col;
            float bv = (gcol < Nhalf) ? biasL[gcol] : biasR[gcol - Nhalf];
            #pragma unroll
            for (int qa = 0; qa < 2; ++qa)
                #pragma unroll
                for (int f = 0; f < 4; ++f)
                    #pragma unroll
                    for (int r = 0; r < 4; ++r) {
                        int row = qa * 128 + wr * 64 + f * 16 + cq + r;
                        int gi = (col >> 4) ^ ((row >> 2) & 7);
                        Ct[row * 256 + gi * 16 + (col & 15)] =
                            (_Float16)(acc[qa][qb][f][g][r] + bv);
                    }
        }
    __syncthreads();
    const int r0 = tid >> 5;
    const int cc = (tid & 31) * 8;
    const int gg = cc >> 4;
    #pragma unroll
    for (int ps = 0; ps < 16; ++ps) {
        int row = ps * 16 + r0;
        int grow = rowBase + row;
        if (grow < Mrows) {
            int gp = gg ^ ((row >> 2) & 7);
            half8 v = *(const half8*)&Ct[row * 256 + gp * 16 + (cc & 15)];
            *(half8*)&C[(size_t)grow * N + colBase + cc] = v;
        }
    }
}

// ---------------- 128x128 MFMA GEMM (proven R2 kernel; layer-3) ------------
__global__ __launch_bounds__(256) void gemm_mfma_f16(
    const _Float16* __restrict__ A0, const _Float16* __restrict__ B0,
    const float* __restrict__ biasL, const float* __restrict__ biasR,
    int Nhalf, _Float16* __restrict__ C,
    int Mrows, int K, int N)
{
    __shared__ __align__(16) _Float16 smem[2 * 2 * 128 * 32];
    _Float16* As = smem;
    _Float16* Bs = smem + 2 * 128 * 32;

    const int tid = threadIdx.x;
    const int wave = tid >> 6;
    const int lane = tid & 63;
    const int wm = (wave >> 1) * 64;
    const int wn = (wave & 1) * 64;
    const int lm = lane & 15;
    const int swz = (((lane >> 4) ^ ((lane >> 1) & 3)) << 3);

    const int rowBase = blockIdx.y * 128;
    const int colBase = blockIdx.x * 128;

    floatx4 acc[4][4];
    #pragma unroll
    for (int i = 0; i < 4; ++i)
        #pragma unroll
        for (int j = 0; j < 4; ++j)
            acc[i][j] = (floatx4){0.f, 0.f, 0.f, 0.f};

    const int sr = lane >> 2;
    const int scol = (((lane & 3) ^ ((lane >> 3) & 3)) << 3);
    const _Float16* gA = A0 + (size_t)(rowBase + wave * 32 + sr) * K + scol;
    const _Float16* gB = B0 + (size_t)(colBase + wave * 32 + sr) * K + scol;
    const size_t skip16 = (size_t)16 * K;
    const int lo0 = (wave * 32) * 32;
    const int lo1 = (wave * 32 + 16) * 32;

    gload_lds16(gA, &As[lo0]);
    gload_lds16(gA + skip16, &As[lo1]);
    gload_lds16(gB, &Bs[lo0]);
    gload_lds16(gB + skip16, &Bs[lo1]);
    __syncthreads();

    const int nk = K >> 5;
    for (int t = 0; t < nk; ++t) {
        const int p = t & 1;
        const int po = p * 128 * 32;
        if (t + 1 < nk) {
            const int k1 = (t + 1) << 5;
            const int qo = (p ^ 1) * 128 * 32;
            gload_lds16(gA + k1, &As[qo + lo0]);
            gload_lds16(gA + skip16 + k1, &As[qo + lo1]);
            gload_lds16(gB + k1, &Bs[qo + lo0]);
            gload_lds16(gB + skip16 + k1, &Bs[qo + lo1]);
        }
        half8 a0[4], b0[4];
        #pragma unroll
        for (int i = 0; i < 4; ++i) {
            a0[i] = *(const half8*)&As[po + (wm + i * 16 + lm) * 32 + swz];
            b0[i] = *(const half8*)&Bs[po + (wn + i * 16 + lm) * 32 + swz];
        }
        #pragma unroll
        for (int i = 0; i < 4; ++i)
            #pragma unroll
            for (int j = 0; j < 4; ++j)
                acc[i][j] = __builtin_amdgcn_mfma_f32_16x16x32_f16(a0[i], b0[j], acc[i][j], 0, 0, 0);
        __syncthreads();
    }

    _Float16* Ct = smem;
    const int cq = (lane >> 4) * 4;
    #pragma unroll
    for (int j = 0; j < 4; ++j) {
        int col = wn + j * 16 + lm;
        int gcol = colBase + col;
        float bv = (gcol < Nhalf) ? biasL[gcol] : biasR[gcol - Nhalf];
        #pragma unroll
        for (int i = 0; i < 4; ++i) {
            int row = wm + i * 16 + cq;
            #pragma unroll
            for (int r = 0; r < 4; ++r) {
                int rr = row + r;
                Ct[rr * 128 + (col ^ (((rr >> 2) & 7) << 4))] = (_Float16)(acc[i][j][r] + bv);
            }
        }
    }
    __syncthreads();
    const int r0 = tid >> 4;
    const int cc = (tid & 15) * 8;
    #pragma unroll
    for (int ps = 0; ps < 8; ++ps) {
        int row = ps * 16 + r0;
        int grow = rowBase + row;
        if (grow < Mrows) {
            half8 v = *(const half8*)&Ct[row * 128 + (cc ^ (((row >> 2) & 7) << 4))];
            *(half8*)&C[(size_t)grow * N + colBase + cc] = v;
        }
    }
}

// ---------------- CSR build ----------------

__global__ void k_build_zero(const int* __restrict__ ei, int* __restrict__ src,
                             int* __restrict__ dst, int* __restrict__ cnt,
                             int* __restrict__ gstart, float* __restrict__ hpool) {
    int i = blockIdx.x * 256 + threadIdx.x;
    if (i < NE) { src[i] = ei[i]; dst[i] = ei[NE + i]; }
    else if (i < NEE) { src[i] = i - NE; dst[i] = i - NE; }
    if (i < NN) cnt[i] = 0;
    if (i < 2 * NG) gstart[i] = 0;
    if (i < NG * 256) hpool[i] = 0.f;
}

__global__ void k_count(const int* __restrict__ dst, int* __restrict__ cnt) {
    int i = blockIdx.x * 256 + threadIdx.x;
    if (i < NEE) atomicAdd(&cnt[dst[i]], 1);
}

__global__ __launch_bounds__(256) void k_scan(const int* __restrict__ cnt,
                                              int* __restrict__ off, int* __restrict__ cur) {
    __shared__ int partial[256];
    __shared__ int ppre[257];
    int t = threadIdx.x;
    const int chunk = (NN + 255) / 256;
    int lo = t * chunk, hi = min(NN, (t + 1) * chunk);
    int s = 0;
    for (int i = lo; i < hi; ++i) s += cnt[i];
    partial[t] = s;
    __syncthreads();
    if (t == 0) {
        int acc = 0;
        for (int i = 0; i < 256; ++i) { ppre[i] = acc; acc += partial[i]; }
        ppre[256] = acc;
    }
    __syncthreads();
    int acc = ppre[t];
    for (int i = lo; i < hi; ++i) { off[i] = acc; cur[i] = acc; acc += cnt[i]; }
    if (t == 0) off[NN] = ppre[256];
}

__global__ void k_fill(const int* __restrict__ src, const int* __restrict__ dst,
                       int* __restrict__ cur, int* __restrict__ slist) {
    int e = blockIdx.x * 256 + threadIdx.x;
    if (e < NEE) { int p = atomicAdd(&cur[dst[e]], 1); slist[p] = src[e]; }
}

// ---------------- fused GATv2 edge pipeline (fp16 activations) -------------
// xlr row n = [xl(n) | xr(n)], stride LD = 2*NH*C.
// R11: serial-chain attack (evidence: R10's __expf shaved measurable time ->
// chain-bound). (a) batch-of-3 scoring: the 3 wave-reductions are
// independent, waveSum3 interleaves the shfl chains (~250cy/3 edges vs
// 600 serial). Batches are double-buffered (cur/nxt) so gather latency
// stays hidden. (b) defer-max (T13, THR=0): rescale path only when the
// running max grows; common path = den+=ex, acc+=ex*xv (PL fma). Branch is
// wave-uniform (post-reduction scalar). Math identical.
template<int C>
__global__ __launch_bounds__(256) void k_gat_fused(
    const _Float16* __restrict__ xlr, const _Float16* __restrict__ att,
    const int* __restrict__ eoff, const int* __restrict__ slist,
    const float* __restrict__ bias, _Float16* __restrict__ out)
{
    constexpr int LD = 2 * NH * C;          // fused GEMM row stride (halfs)
    constexpr int CH = (C >= 512) ? 8 : 4;  // halfs per load per lane
    constexpr int NC = C / (64 * CH);       // chunks per head-row
    constexpr int PL = NC * CH;             // elems per lane
    __shared__ float red[NH * C];
    const int n = blockIdx.x;
    const int h = threadIdx.x >> 6;
    const int lane = threadIdx.x & 63;

    float xrv[PL], attv[PL], acc[PL];
    {
        const _Float16* xrrow = xlr + (size_t)n * LD + NH * C + h * C + lane * CH;
        const _Float16* ah = att + h * C + lane * CH;
        #pragma unroll
        for (int c = 0; c < NC; ++c) {
            if constexpr (CH == 8) {
                half8 hv = *(const half8*)(xrrow + c * 64 * CH);
                half8 av = *(const half8*)(ah + c * 64 * CH);
                #pragma unroll
                for (int e = 0; e < 8; ++e) {
                    xrv[c * 8 + e] = (float)hv[e];
                    attv[c * 8 + e] = (float)av[e];
                }
            } else {
                half4 hv = *(const half4*)(xrrow + c * 64 * CH);
                half4 av = *(const half4*)(ah + c * 64 * CH);
                #pragma unroll
                for (int e = 0; e < 4; ++e) {
                    xrv[c * 4 + e] = (float)hv[e];
                    attv[c * 4 + e] = (float)av[e];
                }
            }
        }
        #pragma unroll
        for (int e = 0; e < PL; ++e) acc[e] = 0.f;
    }

    float m = -INFINITY, den = 0.f;
    const int start = eoff[n], end = eoff[n + 1];

    _Float16 c0[PL], c1[PL], c2[PL], x0[PL], x1b[PL], x2[PL];
    auto ldrow = [&](int s, _Float16* buf) {
        const _Float16* p = xlr + (size_t)s * LD + h * C + lane * CH;
        #pragma unroll
        for (int c = 0; c < NC; ++c) {
            if constexpr (CH == 8)
                *(half8*)&buf[c * 8] = *(const half8*)(p + c * 64 * CH);
            else
                *(half4*)&buf[c * 4] = *(const half4*)(p + c * 64 * CH);
        }
    };
    auto score = [&](const _Float16* buf) -> float {
        float ps = 0.f;
        #pragma unroll
        for (int e = 0; e < PL; ++e) {
            float v = (float)buf[e] + xrv[e];
            v = v > 0.f ? v : 0.2f * v;
            ps = fmaf(v, attv[e], ps);
        }
        return ps;
    };
    auto update = [&](float ps, const _Float16* buf) {
        if (ps > m) {            // wave-uniform (ps is post-reduction scalar)
            float scale = __expf(m - ps);   // m=-inf -> 0 (first edge ok)
            den = den * scale + 1.f;        // ex = exp(0) = 1
            #pragma unroll
            for (int e = 0; e < PL; ++e)
                acc[e] = fmaf(acc[e], scale, (float)buf[e]);
            m = ps;
        } else {
            float ex = __expf(ps - m);
            den += ex;
            #pragma unroll
            for (int e = 0; e < PL; ++e)
                acc[e] = fmaf(ex, (float)buf[e], acc[e]);
        }
    };

    int j = start;
    int nb = (end - j) < 3 ? (end - j) : 3;
    if (nb > 0) ldrow(slist[j], c0);
    if (nb > 1) ldrow(slist[j + 1], c1);
    if (nb > 2) ldrow(slist[j + 2], c2);
    while (j < end) {
        int jn = j + nb;
        int nbn = (end - jn) < 3 ? (end - jn) : 3;
        if (nbn > 0) ldrow(slist[jn], x0);       // prefetch next batch
        if (nbn > 1) ldrow(slist[jn + 1], x1b);
        if (nbn > 2) ldrow(slist[jn + 2], x2);
        float p0 = score(c0);
        float p1 = (nb > 1) ? score(c1) : 0.f;
        float p2 = (nb > 2) ? score(c2) : 0.f;
        waveSum3(p0, p1, p2);
        update(p0, c0);
        if (nb > 1) update(p1, c1);
        if (nb > 2) update(p2, c2);
        #pragma unroll
        for (int e = 0; e < PL; ++e) { c0[e] = x0[e]; c1[e] = x1b[e]; c2[e] = x2[e]; }
        j = jn; nb = nbn;
    }

    float inv = 1.f / (den + 1e-16f);
    #pragma unroll
    for (int c = 0; c < NC; ++c) {
        int off = h * C + c * 64 * CH + lane * CH;
        #pragma unroll
        for (int e = 0; e < CH; e += 4) {
            float4 r;
            r.x = acc[c * CH + e + 0] * inv;
            r.y = acc[c * CH + e + 1] * inv;
            r.z = acc[c * CH + e + 2] * inv;
            r.w = acc[c * CH + e + 3] * inv;
            *(float4*)&red[off + e] = r;
        }
    }
    __syncthreads();

    int t = threadIdx.x;
    for (int c4 = t; c4 < C / 4; c4 += 256) {
        int c = c4 * 4;
        float4 r0 = *(const float4*)&red[0 * C + c];
        float4 r1 = *(const float4*)&red[1 * C + c];
        float4 r2 = *(const float4*)&red[2 * C + c];
        float4 r3 = *(const float4*)&red[3 * C + c];
        float4 bv = *(const float4*)(bias + c);
        half4 o;
        o[0] = (_Float16)fmaxf((r0.x + r1.x + r2.x + r3.x) * 0.25f + bv.x, 0.f);
        o[1] = (_Float16)fmaxf((r0.y + r1.y + r2.y + r3.y) * 0.25f + bv.y, 0.f);
        o[2] = (_Float16)fmaxf((r0.z + r1.z + r2.z + r3.z) * 0.25f + bv.z, 0.f);
        o[3] = (_Float16)fmaxf((r0.w + r1.w + r2.w + r3.w) * 0.25f + bv.w, 0.f);
        *(half4*)(out + (size_t)n * C + c) = o;
    }
}

// ---------------- gate + pool + MLP ----------------

__global__ __launch_bounds__(128) void k_gate(
    const _Float16* __restrict__ x, const float* __restrict__ Wg0,
    const float* __restrict__ bg0, const float* __restrict__ Wg1,
    const float* __restrict__ bg1, float* __restrict__ g)
{
    int n = blockIdx.x;
    int t = threadIdx.x;
    __shared__ float xs[256];
    __shared__ float wsum[2];
    const _Float16* xp = x + (size_t)n * 256;
    xs[t] = (float)xp[t]; xs[t + 128] = (float)xp[t + 128];
    __syncthreads();
    float acc = bg0[t];
    for (int k = 0; k < 256; ++k) acc = fmaf(xs[k], Wg0[k * 128 + t], acc);
    acc = acc > 0.f ? acc : 0.f;
    float prod = acc * Wg1[t];
    prod = waveSum(prod);
    if ((t & 63) == 0) wsum[t >> 6] = prod;
    __syncthreads();
    if (t == 0) g[n] = wsum[0] + wsum[1] + bg1[0];
}

__global__ void k_group_bounds(const int* __restrict__ batch, int* __restrict__ gstart,
                               int* __restrict__ gend) {
    int n = blockIdx.x * 256 + threadIdx.x;
    if (n >= NN) return;
    int b = batch[n];
    if (n == 0 || batch[n - 1] != b) gstart[b] = n;
    if (n == NN - 1 || batch[n + 1] != b) gend[b] = n + 1;
}

// per-group softmax stats: m[g], invden[g]
__global__ __launch_bounds__(256) void k_pool_stats(
    const float* __restrict__ g, const int* __restrict__ gstart,
    const int* __restrict__ gend, float* __restrict__ mOut,
    float* __restrict__ invdenOut)
{
    int gi = blockIdx.x;
    int t = threadIdx.x;
    int s0 = gstart[gi], e0 = gend[gi];
    __shared__ float red[4];
    float mx = -1e30f;
    for (int n = s0 + t; n < e0; n += 256) mx = fmaxf(mx, g[n]);
    float wm = waveMax(mx);
    if ((t & 63) == 0) red[t >> 6] = wm;
    __syncthreads();
    float m = fmaxf(fmaxf(red[0], red[1]), fmaxf(red[2], red[3]));
    __syncthreads();
    float sm = 0.f;
    for (int n = s0 + t; n < e0; n += 256) sm += expf(g[n] - m);
    sm = waveSum(sm);
    if ((t & 63) == 0) red[t >> 6] = sm;
    __syncthreads();
    if (t == 0) {
        float den = red[0] + red[1] + red[2] + red[3] + 1e-16f;
        mOut[gi] = m;
        invdenOut[gi] = 1.f / den;
    }
}

#define PCH 16
__global__ __launch_bounds__(256) void k_pool_acc(
    const _Float16* __restrict__ x, const float* __restrict__ g,
    const int* __restrict__ batch, const float* __restrict__ m,
    const float* __restrict__ invden, float* __restrict__ hpool)
{
    int base = blockIdx.x * PCH;
    int t = threadIdx.x;
    float acc = 0.f;
    int cur = -1;
    for (int i = 0; i < PCH; ++i) {
        int n = base + i;
        if (n >= NN) break;
        int b = batch[n];
        if (b != cur) {
            if (cur >= 0) atomicAdd(&hpool[cur * 256 + t], acc);
            cur = b; acc = 0.f;
        }
        float w = expf(g[n] - m[b]) * invden[b];
        acc = fmaf(w, (float)x[(size_t)n * 256 + t], acc);
    }
    if (cur >= 0) atomicAdd(&hpool[cur * 256 + t], acc);
}

__global__ __launch_bounds__(256) void k_mlp(
    const float* __restrict__ hpool,
    const float* __restrict__ Wm0, const float* __restrict__ bm0,
    const float* __restrict__ Wm1, const float* __restrict__ bm1,
    const float* __restrict__ Wm2, const float* __restrict__ bm2,
    const float* __restrict__ Wm3, const float* __restrict__ bm3,
    const float* __restrict__ Wm4, const float* __restrict__ bm4,
    float* __restrict__ out)
{
    __shared__ float bufA[8 * 256];
    __shared__ float bufB[8 * 128];
    int t = threadIdx.x;
    for (int i = t; i < 8 * 256; i += 256) bufA[i] = hpool[i];
    __syncthreads();
    for (int i = t; i < 8 * 128; i += 256) {
        int r = i >> 7, c = i & 127;
        float acc = bm0[c];
        for (int k = 0; k < 256; ++k) acc = fmaf(bufA[r * 256 + k], Wm0[k * 128 + c], acc);
        bufB[i] = fmaxf(acc, 0.f);
    }
    __syncthreads();
    for (int i = t; i < 8 * 64; i += 256) {
        int r = i >> 6, c = i & 63;
        float acc = bm1[c];
        for (int k = 0; k < 128; ++k) acc = fmaf(bufB[r * 128 + k], Wm1[k * 64 + c], acc);
        bufA[i] = fmaxf(acc, 0.f);
    }
    __syncthreads();
    for (int i = t; i < 8 * 32; i += 256) {
        int r = i >> 5, c = i & 31;
        float acc = bm2[c];
        for (int k = 0; k < 64; ++k) acc = fmaf(bufA[r * 64 + k], Wm2[k * 32 + c], acc);
        bufB[i] = fmaxf(acc, 0.f);
    }
    __syncthreads();
    for (int i = t; i < 8 * 16; i += 256) {
        int r = i >> 4, c = i & 15;
        float acc = bm3[c];
        for (int k = 0; k < 32; ++k) acc = fmaf(bufB[r * 32 + k], Wm3[k * 16 + c], acc);
        bufA[i] = fmaxf(acc, 0.f);
    }
    __syncthreads();
    if (t < 8) {
        float acc = bm4[0];
        for (int k = 0; k < 16; ++k) acc = fmaf(bufA[t * 16 + k], Wm4[k], acc);
        out[t] = acc;
    }
}

// ---------------- host orchestration ----------------

static void run_gat_layer(const _Float16* ain, int K, int C,
                          const float* Wl, const float* bl,
                          const float* Wr, const float* br,
                          const _Float16* attH, const float* bias,
                          _Float16* wb0, _Float16* xlr,
                          const int* eoff, const int* slist,
                          _Float16* xout, hipStream_t stream)
{
    int HC = NH * C;
    dim3 tgrid(HC / 32, K / 32, 2);
    k_cvtWT2<<<tgrid, 256, 0, stream>>>(Wl, Wr, wb0, K, HC);
    // fused Wl/Wr GEMM: N = 2*HC, output row n = [xl(n) | xr(n)]
    if (C >= 512) {
        dim3 ggrid(2 * HC / 256, NNP / 256);
        gemm256_mfma_f16<<<ggrid, 512, 0, stream>>>(ain, wb0, bl, br, HC, xlr, NN, K, 2 * HC);
    } else {
        dim3 ggrid(2 * HC / 128, NNP / 128);
        gemm_mfma_f16<<<ggrid, 256, 0, stream>>>(ain, wb0, bl, br, HC, xlr, NN, K, 2 * HC);
    }

    if (C == 1024)
        k_gat_fused<1024><<<NN, 256, 0, stream>>>(xlr, attH, eoff, slist, bias, xout);
    else if (C == 512)
        k_gat_fused<512><<<NN, 256, 0, stream>>>(xlr, attH, eoff, slist, bias, xout);
    else
        k_gat_fused<256><<<NN, 256, 0, stream>>>(xlr, attH, eoff, slist, bias, xout);
}

extern "C" void kernel_launch(void* const* d_in, const int* in_sizes, int n_in,
                              void* d_out, int out_size, void* d_ws, size_t ws_size,
                              hipStream_t stream) {
    const float* x      = (const float*)d_in[0];
    const int* ei       = (const int*)d_in[1];
    const int* batch    = (const int*)d_in[2];
    const float* Wl1 = (const float*)d_in[3];  const float* bl1 = (const float*)d_in[4];
    const float* Wr1 = (const float*)d_in[5];  const float* br1 = (const float*)d_in[6];
    const float* att1= (const float*)d_in[7];  const float* b1  = (const float*)d_in[8];
    const float* Wl2 = (const float*)d_in[9];  const float* bl2 = (const float*)d_in[10];
    const float* Wr2 = (const float*)d_in[11]; const float* br2 = (const float*)d_in[12];
    const float* att2= (const float*)d_in[13]; const float* b2  = (const float*)d_in[14];
    const float* Wl3 = (const float*)d_in[15]; const float* bl3 = (const float*)d_in[16];
    const float* Wr3 = (const float*)d_in[17]; const float* br3 = (const float*)d_in[18];
    const float* att3= (const float*)d_in[19]; const float* b3  = (const float*)d_in[20];
    const float* Wm0 = (const float*)d_in[21]; const float* bm0 = (const float*)d_in[22];
    const float* Wm1 = (const float*)d_in[23]; const float* bm1 = (const float*)d_in[24];
    const float* Wm2 = (const float*)d_in[25]; const float* bm2 = (const float*)d_in[26];
    const float* Wm3 = (const float*)d_in[27]; const float* bm3 = (const float*)d_in[28];
    const float* Wm4 = (const float*)d_in[29]; const float* bm4 = (const float*)d_in[30];
    const float* Wg0 = (const float*)d_in[31]; const float* bg0 = (const float*)d_in[32];
    const float* Wg1 = (const float*)d_in[33]; const float* bg1 = (const float*)d_in[34];
    float* out = (float*)d_out;

    // workspace carve (float units = 4B); fp16 buffers 16B-aligned, padded rows
    float* ws = (float*)d_ws;
    size_t o = 0;
    _Float16* xlr = (_Float16*)(ws + o); o += (size_t)NNP * 8192 / 2;  // fused [xl|xr], layer1 sized
    _Float16* x1  = (_Float16*)(ws + o); o += (size_t)NNP * 1024 / 2;
    _Float16* x2  = (_Float16*)(ws + o); o += (size_t)NNP * 512 / 2;
    _Float16* x3  = (_Float16*)(ws + o); o += (size_t)NNP * 256 / 2;
    _Float16* a0p = (_Float16*)(ws + o); o += (size_t)NNP * 1536 / 2;
    _Float16* wb0 = (_Float16*)(ws + o); o += (size_t)8192 * 1536 / 2; // [WlT | WrT], layer1 sized
    _Float16* attH= (_Float16*)(ws + o); o += 8192 / 2;                // [att1|att2|att3] fp16
    int* srcA    = (int*)(ws + o); o += NEE;
    int* dstA    = (int*)(ws + o); o += NEE;
    int* cnt     = (int*)(ws + o); o += NN;
    int* eoff    = (int*)(ws + o); o += NN + 1;
    int* cur     = (int*)(ws + o); o += NN;
    int* slist   = (int*)(ws + o); o += NEE;
    float* g     = ws + o; o += NN;
    int* gstart  = (int*)(ws + o); o += NG;
    int* gend    = (int*)(ws + o); o += NG;
    float* gm    = ws + o; o += NG;
    float* ginv  = ws + o; o += NG;
    float* hpool = ws + o; o += NG * 256;

    // build CSR by dst (slist holds src node ids) + all zeroing in one pass
    int ebB = (NEE + 255) / 256;
    k_build_zero<<<ebB, 256, 0, stream>>>(ei, srcA, dstA, cnt, gstart, hpool);
    k_count<<<ebB, 256, 0, stream>>>(dstA, cnt);
    k_scan<<<1, 256, 0, stream>>>(cnt, eoff, cur);
    k_fill<<<ebB, 256, 0, stream>>>(srcA, dstA, cur, slist);

    // att -> fp16 (once, all three layers)
    k_cvt_att3<<<28, 256, 0, stream>>>(att1, att2, att3, attH);

    // layer-1 input -> fp16 (only conversion needed; later layers emit fp16)
    int nA = NN * 1536;
    k_cvtA<<<(nA + 255) / 256, 256, 0, stream>>>(x, a0p, nA);

    // three GATv2 layers
    run_gat_layer(a0p, 1536, 1024, Wl1, bl1, Wr1, br1, attH, b1,
                  wb0, xlr, eoff, slist, x1, stream);
    run_gat_layer(x1,  1024, 512,  Wl2, bl2, Wr2, br2, attH + 4096, b2,
                  wb0, xlr, eoff, slist, x2, stream);
    run_gat_layer(x2,  512,  256,  Wl3, bl3, Wr3, br3, attH + 6144, b3,
                  wb0, xlr, eoff, slist, x3, stream);

    // gate + pool + MLP
    k_gate<<<NN, 128, 0, stream>>>(x3, Wg0, bg0, Wg1, bg1, g);
    k_group_bounds<<<(NN + 255) / 256, 256, 0, stream>>>(batch, gstart, gend);
    k_pool_stats<<<NG, 256, 0, stream>>>(g, gstart, gend, gm, ginv);
    k_pool_acc<<<(NN + PCH - 1) / PCH, 256, 0, stream>>>(x3, g, batch, gm, ginv, hpool);
    k_mlp<<<1, 256, 0, stream>>>(hpool, Wm0, bm0, Wm1, bm1, Wm2, bm2,
                                 Wm3, bm3, Wm4, bm4, out);
}